// Round 2
// baseline (140657.800 us; speedup 1.0000x reference)
//
#include <hip/hip_runtime.h>
#include <math.h>

// ---------------------------------------------------------------------------
// Encoder: 2-layer bidirectional LSTM, B=64, T=512, E=H=512, fp32 in/out.
// Round 2: fix ws OOB (688 MB -> 208 MB). xz + l1 stored bf16, sequential
// directions sharing one xz buffer, recurrence = 128 persistent blocks.
// ---------------------------------------------------------------------------

#define NBLK_LSTM 128

__device__ __forceinline__ float bf2f(unsigned short u) {
  return __uint_as_float(((unsigned)u) << 16);
}
__device__ __forceinline__ unsigned short f2bf(float f) {
  unsigned u = __float_as_uint(f);
  unsigned r = (u + 0x7FFFu + ((u >> 16) & 1u)) >> 16;
  return (unsigned short)r;
}

// ---------------- grid barrier (generation counter) -------------------------
__device__ __forceinline__ void gridbar(unsigned* cnt, unsigned* gen, unsigned nblk) {
  __syncthreads();
  if (threadIdx.x == 0) {
    unsigned g = __hip_atomic_load(gen, __ATOMIC_RELAXED, __HIP_MEMORY_SCOPE_AGENT);
    unsigned a = __hip_atomic_fetch_add(cnt, 1u, __ATOMIC_ACQ_REL, __HIP_MEMORY_SCOPE_AGENT) + 1u;
    if (a == nblk) {
      __hip_atomic_store(cnt, 0u, __ATOMIC_RELAXED, __HIP_MEMORY_SCOPE_AGENT);
      __hip_atomic_fetch_add(gen, 1u, __ATOMIC_RELEASE, __HIP_MEMORY_SCOPE_AGENT);
    } else {
      while (__hip_atomic_load(gen, __ATOMIC_ACQUIRE, __HIP_MEMORY_SCOPE_AGENT) == g) {
        __builtin_amdgcn_s_sleep(8);
      }
    }
  }
  __syncthreads();
}

// ---------------- U transpose: Ut[col][k] = U[k][col] (fp32) ----------------
__global__ __launch_bounds__(256) void transpose_u(const float* __restrict__ U,
                                                   float* __restrict__ Ut) {
  __shared__ float tile[32][33];
  int kt = blockIdx.x & 15;        // 512/32
  int ct = blockIdx.x >> 4;        // 2048/32
  int k0 = kt * 32, c0 = ct * 32;
  int tx = threadIdx.x & 31, ty = threadIdx.x >> 5;   // 32 x 8
#pragma unroll
  for (int i = 0; i < 32; i += 8)
    tile[ty + i][tx] = U[(size_t)(k0 + ty + i) * 2048 + c0 + tx];
  __syncthreads();
#pragma unroll
  for (int i = 0; i < 32; i += 8)
    Ut[(size_t)(c0 + ty + i) * 512 + k0 + tx] = tile[tx][ty + i];
}

// ---------------- GEMM: C_bf16[M,2048] = A[M,K] @ W[K,2048] + bias ----------
// M = 32768. TM=128, TN=64, TK=16, 256 threads, 8x4 microtile.
// ABF16: A is bf16 [M][K]; else A is fp32 (with optional row gather, K=512).
template <bool ABF16>
__global__ __launch_bounds__(256) void gemm_bias(const void* __restrict__ Av,
                                                 const float* __restrict__ W,
                                                 const float* __restrict__ bias,
                                                 unsigned short* __restrict__ C,
                                                 int K,
                                                 const int* __restrict__ gather) {
  __shared__ float As[16][132];
  __shared__ float Bs[16][68];
  const int bm = blockIdx.x & 255;   // 256 m-blocks
  const int bn = blockIdx.x >> 8;    // 32 n-blocks
  const int m0 = bm * 128, n0 = bn * 64;
  const int tid = threadIdx.x;
  const int tx = tid & 15, ty = tid >> 4;

  float acc[8][4];
#pragma unroll
  for (int r = 0; r < 8; r++)
#pragma unroll
    for (int q = 0; q < 4; q++) acc[r][q] = 0.0f;

  for (int k0 = 0; k0 < K; k0 += 16) {
#pragma unroll
    for (int s = 0; s < 2; s++) {
      int slot = tid + s * 256;              // 0..511: 128 rows x 4 k-groups
      int row = slot >> 2;
      int f4 = (slot & 3) * 4;
      if (ABF16) {
        const unsigned short* A = (const unsigned short*)Av;
        size_t abase = (size_t)(m0 + row) * K;
        ushort4 v = *(const ushort4*)&A[abase + k0 + f4];
        As[f4 + 0][row] = bf2f(v.x);
        As[f4 + 1][row] = bf2f(v.y);
        As[f4 + 2][row] = bf2f(v.z);
        As[f4 + 3][row] = bf2f(v.w);
      } else {
        const float* A = (const float*)Av;
        size_t abase = gather ? ((size_t)gather[m0 + row] * 512)
                              : ((size_t)(m0 + row) * K);
        float4 v = *(const float4*)&A[abase + k0 + f4];
        As[f4 + 0][row] = v.x;
        As[f4 + 1][row] = v.y;
        As[f4 + 2][row] = v.z;
        As[f4 + 3][row] = v.w;
      }
    }
    {
      int kr = tid >> 4;
      int nf = (tid & 15) * 4;
      *(float4*)&Bs[kr][nf] = *(const float4*)&W[(size_t)(k0 + kr) * 2048 + n0 + nf];
    }
    __syncthreads();
#pragma unroll
    for (int k = 0; k < 16; k++) {
      float4 a0 = *(const float4*)&As[k][ty * 8];
      float4 a1 = *(const float4*)&As[k][ty * 8 + 4];
      float4 b0 = *(const float4*)&Bs[k][tx * 4];
      float av[8] = {a0.x, a0.y, a0.z, a0.w, a1.x, a1.y, a1.z, a1.w};
      float bv[4] = {b0.x, b0.y, b0.z, b0.w};
#pragma unroll
      for (int r = 0; r < 8; r++)
#pragma unroll
        for (int q = 0; q < 4; q++)
          acc[r][q] = fmaf(av[r], bv[q], acc[r][q]);
    }
    __syncthreads();
  }

  float4 bb = *(const float4*)&bias[n0 + tx * 4];
#pragma unroll
  for (int r = 0; r < 8; r++) {
    ushort4 o;
    o.x = f2bf(acc[r][0] + bb.x);
    o.y = f2bf(acc[r][1] + bb.y);
    o.z = f2bf(acc[r][2] + bb.z);
    o.w = f2bf(acc[r][3] + bb.w);
    *(ushort4*)&C[(size_t)(m0 + ty * 8 + r) * 2048 + n0 + tx * 4] = o;
  }
}

// ---------------- recurrence: one direction, 128 blocks x 256 threads -------
// Thread owns (b, j): 4 gate dots K=512 vs fp32 Ut. hbuf fp32 [2][64][512].
__device__ __forceinline__ float sigmoidf_(float x) {
  return 1.0f / (1.0f + expf(-x));
}

__global__ __launch_bounds__(256) void lstm_dir_k(
    const unsigned short* __restrict__ xz,   // bf16 [64*512][2048]
    const float* __restrict__ Ut,            // fp32 [4][512 cols][512 k]
    float* __restrict__ hsF,                 // fp32 out (stride 1024) or null
    unsigned short* __restrict__ hsB16,      // bf16 out (stride 1024) or null
    float* __restrict__ hbuf,
    float* __restrict__ stateh, float* __restrict__ statec,
    int reverse, unsigned* __restrict__ bar) {
  const int bid = blockIdx.x;
  const int b = (bid >> 5) * 16 + (threadIdx.x >> 4);   // 0..63
  const int j = (bid & 31) * 16 + (threadIdx.x & 15);   // 0..511

  const float4* u0 = (const float4*)(Ut + 0 * 262144 + (size_t)j * 512);
  const float4* u1 = (const float4*)(Ut + 1 * 262144 + (size_t)j * 512);
  const float4* u2 = (const float4*)(Ut + 2 * 262144 + (size_t)j * 512);
  const float4* u3 = (const float4*)(Ut + 3 * 262144 + (size_t)j * 512);

  float c = 0.0f;
  for (int s = 0; s < 512; s++) {
    const int t = reverse ? (511 - s) : s;
    const unsigned short* xzp = xz + ((size_t)b * 512 + t) * 2048 + j;
    float z0 = bf2f(xzp[0]);
    float z1 = bf2f(xzp[512]);
    float z2 = bf2f(xzp[1024]);
    float z3 = bf2f(xzp[1536]);
    if (s > 0) {
      const float4* hp = (const float4*)(hbuf + (s & 1) * 32768 + (size_t)b * 512);
#pragma unroll 4
      for (int k = 0; k < 128; k++) {
        float4 h4 = hp[k];
        float4 a = u0[k], d = u1[k], e = u2[k], f = u3[k];
        z0 = fmaf(h4.x, a.x, z0); z0 = fmaf(h4.y, a.y, z0);
        z0 = fmaf(h4.z, a.z, z0); z0 = fmaf(h4.w, a.w, z0);
        z1 = fmaf(h4.x, d.x, z1); z1 = fmaf(h4.y, d.y, z1);
        z1 = fmaf(h4.z, d.z, z1); z1 = fmaf(h4.w, d.w, z1);
        z2 = fmaf(h4.x, e.x, z2); z2 = fmaf(h4.y, e.y, z2);
        z2 = fmaf(h4.z, e.z, z2); z2 = fmaf(h4.w, e.w, z2);
        z3 = fmaf(h4.x, f.x, z3); z3 = fmaf(h4.y, f.y, z3);
        z3 = fmaf(h4.z, f.z, z3); z3 = fmaf(h4.w, f.w, z3);
      }
    }
    float si = sigmoidf_(z0);
    float sf = sigmoidf_(z1);
    float tg = tanhf(z2);
    float so = sigmoidf_(z3);
    c = fmaf(sf, c, si * tg);
    float h = so * tanhf(c);

    hbuf[((s & 1) ^ 1) * 32768 + (size_t)b * 512 + j] = h;
    if (hsB16) hsB16[((size_t)b * 512 + t) * 1024 + j] = f2bf(h);
    else       hsF  [((size_t)b * 512 + t) * 1024 + j] = h;
    if (stateh != nullptr && s == 511) {
      stateh[b * 1024 + j] = h;
      statec[b * 1024 + j] = c;
    }
    if (s < 511) gridbar(bar, bar + 32, NBLK_LSTM);
  }
}

// ---------------------------------------------------------------------------
extern "C" void kernel_launch(void* const* d_in, const int* in_sizes, int n_in,
                              void* d_out, int out_size, void* d_ws, size_t ws_size,
                              hipStream_t stream) {
  const int*   ids = (const int*)d_in[0];
  const float* emb = (const float*)d_in[1];
  const float* W1f = (const float*)d_in[2];
  const float* U1f = (const float*)d_in[3];
  const float* b1f = (const float*)d_in[4];
  const float* W1b = (const float*)d_in[5];
  const float* U1b = (const float*)d_in[6];
  const float* b1b = (const float*)d_in[7];
  const float* W2f = (const float*)d_in[8];
  const float* U2f = (const float*)d_in[9];
  const float* b2f = (const float*)d_in[10];
  const float* W2b = (const float*)d_in[11];
  const float* U2b = (const float*)d_in[12];
  const float* b2b = (const float*)d_in[13];
  float* out = (float*)d_out;

  char* ws = (char*)d_ws;
  // ws layout (bytes), total ~208.3 MB:
  //   xz   bf16 [32768][2048]  @ 0           (134,217,728)
  //   l1   bf16 [32768][1024]  @ 134,217,728 ( 67,108,864)
  //   Ut   fp32 4x[2048][512]  @ 201,326,592 ( 16,777,216)
  //   hbuf fp32 [2][64][512]   @ 218,103,808 (    262,144)
  //   bar                      @ 218,365,952
  unsigned short* xz  = (unsigned short*)(ws + 0ull);
  unsigned short* l1  = (unsigned short*)(ws + 134217728ull);
  float* Ut1f = (float*)(ws + 201326592ull);
  float* Ut1b = Ut1f + 1048576;
  float* Ut2f = Ut1b + 1048576;
  float* Ut2b = Ut2f + 1048576;
  float* hbuf = (float*)(ws + 218103808ull);
  unsigned* bar = (unsigned*)(ws + 218365952ull);

  transpose_u<<<1024, 256, 0, stream>>>(U1f, Ut1f);
  transpose_u<<<1024, 256, 0, stream>>>(U1b, Ut1b);
  transpose_u<<<1024, 256, 0, stream>>>(U2f, Ut2f);
  transpose_u<<<1024, 256, 0, stream>>>(U2b, Ut2b);
  hipMemsetAsync(bar, 0, 256, stream);

  // ---- layer 1 forward ----
  gemm_bias<false><<<8192, 256, 0, stream>>>(emb, W1f, b1f, xz, 512, ids);
  lstm_dir_k<<<NBLK_LSTM, 256, 0, stream>>>(xz, Ut1f, nullptr, l1 + 0, hbuf,
                                            nullptr, nullptr, 0, bar);
  // ---- layer 1 backward ----
  gemm_bias<false><<<8192, 256, 0, stream>>>(emb, W1b, b1b, xz, 512, ids);
  lstm_dir_k<<<NBLK_LSTM, 256, 0, stream>>>(xz, Ut1b, nullptr, l1 + 512, hbuf,
                                            nullptr, nullptr, 1, bar);
  // ---- layer 2 forward ----
  gemm_bias<true><<<8192, 256, 0, stream>>>(l1, W2f, b2f, xz, 1024, nullptr);
  lstm_dir_k<<<NBLK_LSTM, 256, 0, stream>>>(xz, Ut2f, out, nullptr, hbuf,
                                            out + 33554432, out + 33619968, 0, bar);
  // ---- layer 2 backward ----
  gemm_bias<true><<<8192, 256, 0, stream>>>(l1, W2b, b2b, xz, 1024, nullptr);
  lstm_dir_k<<<NBLK_LSTM, 256, 0, stream>>>(xz, Ut2b, out + 512, nullptr, hbuf,
                                            out + 33554432 + 512, out + 33619968 + 512, 1, bar);
}

// Round 3
// 75063.373 us; speedup vs baseline: 1.8739x; 1.8739x over previous
//
#include <hip/hip_runtime.h>
#include <math.h>

// ---------------------------------------------------------------------------
// Encoder: 2-layer bidirectional LSTM, B=64, T=512, E=H=512, fp32 in/out.
// Round 3: recurrence rebuilt — U in LDS (register-tiled 4b x 8c), transposed
// h buffer [k][b] for coalesced loads, in-wave split-K reduce, 2-level barrier.
// ---------------------------------------------------------------------------

#define NBLK_LSTM 256

__device__ __forceinline__ float bf2f(unsigned short u) {
  return __uint_as_float(((unsigned)u) << 16);
}
__device__ __forceinline__ unsigned short f2bf(float f) {
  unsigned u = __float_as_uint(f);
  unsigned r = (u + 0x7FFFu + ((u >> 16) & 1u)) >> 16;
  return (unsigned short)r;
}
__device__ __forceinline__ float sigmoidf_(float x) {
  return 1.0f / (1.0f + expf(-x));
}

// ---------------- 2-level grid barrier --------------------------------------
// bar layout (unsigned words): leaf[i] at bar[i*16] (i=0..7), root at bar[128],
// gen at bar[144]. 256 blocks = 8 leaves x 32.
__device__ __forceinline__ void gridbar2(unsigned* bar) {
  __syncthreads();
  if (threadIdx.x == 0) {
    unsigned* leaf = bar + ((blockIdx.x & 7) << 4);
    unsigned* root = bar + 128;
    unsigned* gen  = bar + 144;
    unsigned g = __hip_atomic_load(gen, __ATOMIC_RELAXED, __HIP_MEMORY_SCOPE_AGENT);
    unsigned a = __hip_atomic_fetch_add(leaf, 1u, __ATOMIC_ACQ_REL,
                                        __HIP_MEMORY_SCOPE_AGENT) + 1u;
    if (a == (NBLK_LSTM / 8)) {
      __hip_atomic_store(leaf, 0u, __ATOMIC_RELAXED, __HIP_MEMORY_SCOPE_AGENT);
      unsigned r = __hip_atomic_fetch_add(root, 1u, __ATOMIC_ACQ_REL,
                                          __HIP_MEMORY_SCOPE_AGENT) + 1u;
      if (r == 8u) {
        __hip_atomic_store(root, 0u, __ATOMIC_RELAXED, __HIP_MEMORY_SCOPE_AGENT);
        __hip_atomic_fetch_add(gen, 1u, __ATOMIC_RELEASE, __HIP_MEMORY_SCOPE_AGENT);
      } else {
        while (__hip_atomic_load(gen, __ATOMIC_ACQUIRE, __HIP_MEMORY_SCOPE_AGENT) == g)
          __builtin_amdgcn_s_sleep(8);
      }
    } else {
      while (__hip_atomic_load(gen, __ATOMIC_ACQUIRE, __HIP_MEMORY_SCOPE_AGENT) == g)
        __builtin_amdgcn_s_sleep(8);
    }
  }
  __syncthreads();
}

// ---------------- U transpose: Ut[col][k] = U[k][col] (fp32) ----------------
__global__ __launch_bounds__(256) void transpose_u(const float* __restrict__ U,
                                                   float* __restrict__ Ut) {
  __shared__ float tile[32][33];
  int kt = blockIdx.x & 15;        // 512/32
  int ct = blockIdx.x >> 4;        // 2048/32
  int k0 = kt * 32, c0 = ct * 32;
  int tx = threadIdx.x & 31, ty = threadIdx.x >> 5;   // 32 x 8
#pragma unroll
  for (int i = 0; i < 32; i += 8)
    tile[ty + i][tx] = U[(size_t)(k0 + ty + i) * 2048 + c0 + tx];
  __syncthreads();
#pragma unroll
  for (int i = 0; i < 32; i += 8)
    Ut[(size_t)(c0 + ty + i) * 512 + k0 + tx] = tile[tx][ty + i];
}

// ---------------- GEMM: C_bf16[M,2048] = A[M,K] @ W[K,2048] + bias ----------
// M = 32768. TM=128, TN=64, TK=16, 256 threads, 8x4 microtile.
template <bool ABF16>
__global__ __launch_bounds__(256) void gemm_bias(const void* __restrict__ Av,
                                                 const float* __restrict__ W,
                                                 const float* __restrict__ bias,
                                                 unsigned short* __restrict__ C,
                                                 int K,
                                                 const int* __restrict__ gather) {
  __shared__ float As[16][132];
  __shared__ float Bs[16][68];
  const int bm = blockIdx.x & 255;
  const int bn = blockIdx.x >> 8;
  const int m0 = bm * 128, n0 = bn * 64;
  const int tid = threadIdx.x;
  const int tx = tid & 15, ty = tid >> 4;

  float acc[8][4];
#pragma unroll
  for (int r = 0; r < 8; r++)
#pragma unroll
    for (int q = 0; q < 4; q++) acc[r][q] = 0.0f;

  for (int k0 = 0; k0 < K; k0 += 16) {
#pragma unroll
    for (int s = 0; s < 2; s++) {
      int slot = tid + s * 256;
      int row = slot >> 2;
      int f4 = (slot & 3) * 4;
      if (ABF16) {
        const unsigned short* A = (const unsigned short*)Av;
        size_t abase = (size_t)(m0 + row) * K;
        ushort4 v = *(const ushort4*)&A[abase + k0 + f4];
        As[f4 + 0][row] = bf2f(v.x);
        As[f4 + 1][row] = bf2f(v.y);
        As[f4 + 2][row] = bf2f(v.z);
        As[f4 + 3][row] = bf2f(v.w);
      } else {
        const float* A = (const float*)Av;
        size_t abase = gather ? ((size_t)gather[m0 + row] * 512)
                              : ((size_t)(m0 + row) * K);
        float4 v = *(const float4*)&A[abase + k0 + f4];
        As[f4 + 0][row] = v.x;
        As[f4 + 1][row] = v.y;
        As[f4 + 2][row] = v.z;
        As[f4 + 3][row] = v.w;
      }
    }
    {
      int kr = tid >> 4;
      int nf = (tid & 15) * 4;
      *(float4*)&Bs[kr][nf] = *(const float4*)&W[(size_t)(k0 + kr) * 2048 + n0 + nf];
    }
    __syncthreads();
#pragma unroll
    for (int k = 0; k < 16; k++) {
      float4 a0 = *(const float4*)&As[k][ty * 8];
      float4 a1 = *(const float4*)&As[k][ty * 8 + 4];
      float4 b0 = *(const float4*)&Bs[k][tx * 4];
      float av[8] = {a0.x, a0.y, a0.z, a0.w, a1.x, a1.y, a1.z, a1.w};
      float bv[4] = {b0.x, b0.y, b0.z, b0.w};
#pragma unroll
      for (int r = 0; r < 8; r++)
#pragma unroll
        for (int q = 0; q < 4; q++)
          acc[r][q] = fmaf(av[r], bv[q], acc[r][q]);
    }
    __syncthreads();
  }

  float4 bb = *(const float4*)&bias[n0 + tx * 4];
#pragma unroll
  for (int r = 0; r < 8; r++) {
    ushort4 o;
    o.x = f2bf(acc[r][0] + bb.x);
    o.y = f2bf(acc[r][1] + bb.y);
    o.z = f2bf(acc[r][2] + bb.z);
    o.w = f2bf(acc[r][3] + bb.w);
    *(ushort4*)&C[(size_t)(m0 + ty * 8 + r) * 2048 + n0 + tx * 4] = o;
  }
}

// ---------------- recurrence (one direction) --------------------------------
// 256 blocks x 256 threads. Block owns j = {2*bid, 2*bid+1} (8 U-cols in LDS).
// Thread (seg=tid>>4, bg=tid&15): 4b x 8c x 32k register tile.
// hbufT: fp32 [2][512 k][64 b] (transposed for coalesced loads).
__global__ __launch_bounds__(256) void lstm_dir_k(
    const unsigned short* __restrict__ xz,   // bf16 [64*512][2048]
    const float* __restrict__ Ut,            // fp32 [2048 cols][512 k]
    float* __restrict__ hsF,                 // fp32 out (stride 1024) or null
    unsigned short* __restrict__ hsB16,      // bf16 out (stride 1024) or null
    float* __restrict__ hbufT,               // fp32 [2][512][64]
    float* __restrict__ stateh, float* __restrict__ statec,
    int reverse, unsigned* __restrict__ bar) {
  __shared__ float u_lds[32][16][12];   // [i][seg][c(8)+pad4] : 24 KB
  __shared__ float p_lds[4][64 * 9];    // [wave][b*9 + c]     : 9.2 KB

  const int tid = threadIdx.x;
  const int bid = blockIdx.x;
  const int jbase = bid * 2;

  // ---- stage U slice: c=0..7 -> (g=c>>1, jl=c&1); col = g*512 + jbase + jl
  {
    int c = tid >> 5;              // 0..7
    int k0 = (tid & 31) * 16;      // 16-k chunk, stays within one 32-seg
    const int g = c >> 1, jl = c & 1;
    const float* src = Ut + ((size_t)(g * 512 + jbase + jl)) * 512 + k0;
#pragma unroll
    for (int kk = 0; kk < 16; kk++) {
      int k = k0 + kk;
      u_lds[k & 31][k >> 5][c] = src[kk];
    }
  }
  __syncthreads();

  const int seg = tid >> 4;        // 0..15 (k-segment, 32 k each)
  const int bg  = tid & 15;        // b-group
  const int b0  = bg * 4;
  const int bu  = tid >> 1;        // update-phase batch (tid<128)
  const int jl  = tid & 1;
  const int j   = jbase + jl;

  float creg = 0.0f;

  for (int s = 0; s < 512; s++) {
    const int tt = reverse ? (511 - s) : s;

    if (s > 0) {
      float acc[4][8];
#pragma unroll
      for (int bi = 0; bi < 4; bi++)
#pragma unroll
        for (int c = 0; c < 8; c++) acc[bi][c] = 0.0f;

      const float* hrow = hbufT + (size_t)(s & 1) * 32768 + (size_t)seg * 32 * 64 + b0;
#pragma unroll 8
      for (int i = 0; i < 32; i++) {
        float4 h4 = *(const float4*)(hrow + i * 64);
        float4 ua = *(const float4*)&u_lds[i][seg][0];
        float4 ub = *(const float4*)&u_lds[i][seg][4];
        float hv[4] = {h4.x, h4.y, h4.z, h4.w};
        float uv[8] = {ua.x, ua.y, ua.z, ua.w, ub.x, ub.y, ub.z, ub.w};
#pragma unroll
        for (int bi = 0; bi < 4; bi++)
#pragma unroll
          for (int c = 0; c < 8; c++)
            acc[bi][c] = fmaf(hv[bi], uv[c], acc[bi][c]);
      }
      // in-wave reduce over the 4 segs resident in this wave (lane bits 4,5)
#pragma unroll
      for (int bi = 0; bi < 4; bi++)
#pragma unroll
        for (int c = 0; c < 8; c++) {
          float v = acc[bi][c];
          v += __shfl_xor(v, 16);
          v += __shfl_xor(v, 32);
          acc[bi][c] = v;
        }
      if ((tid & 48) == 0) {       // one lane-group per wave
        const int w = tid >> 6;
#pragma unroll
        for (int bi = 0; bi < 4; bi++)
#pragma unroll
          for (int c = 0; c < 8; c++)
            p_lds[w][(b0 + bi) * 9 + c] = acc[bi][c];
      }
    }
    __syncthreads();

    if (tid < 128) {
      const unsigned short* xzp = xz + ((size_t)bu * 512 + tt) * 2048 + j;
      float z0 = bf2f(xzp[0]);
      float z1 = bf2f(xzp[512]);
      float z2 = bf2f(xzp[1024]);
      float z3 = bf2f(xzp[1536]);
      if (s > 0) {
#pragma unroll
        for (int w = 0; w < 4; w++) {
          const float* p = &p_lds[w][bu * 9 + jl];
          z0 += p[0];
          z1 += p[2];
          z2 += p[4];
          z3 += p[6];
        }
      }
      float si = sigmoidf_(z0);
      float sf = sigmoidf_(z1);
      float tg = tanhf(z2);
      float so = sigmoidf_(z3);
      creg = fmaf(sf, creg, si * tg);
      float h = so * tanhf(creg);

      hbufT[(size_t)((s & 1) ^ 1) * 32768 + (size_t)j * 64 + bu] = h;
      if (hsB16) hsB16[((size_t)bu * 512 + tt) * 1024 + j] = f2bf(h);
      else       hsF [((size_t)bu * 512 + tt) * 1024 + j] = h;
      if (stateh != nullptr && s == 511) {
        stateh[bu * 1024 + j] = h;
        statec[bu * 1024 + j] = creg;
      }
    }
    if (s < 511) gridbar2(bar);
  }
}

// ---------------------------------------------------------------------------
extern "C" void kernel_launch(void* const* d_in, const int* in_sizes, int n_in,
                              void* d_out, int out_size, void* d_ws, size_t ws_size,
                              hipStream_t stream) {
  const int*   ids = (const int*)d_in[0];
  const float* emb = (const float*)d_in[1];
  const float* W1f = (const float*)d_in[2];
  const float* U1f = (const float*)d_in[3];
  const float* b1f = (const float*)d_in[4];
  const float* W1b = (const float*)d_in[5];
  const float* U1b = (const float*)d_in[6];
  const float* b1b = (const float*)d_in[7];
  const float* W2f = (const float*)d_in[8];
  const float* U2f = (const float*)d_in[9];
  const float* b2f = (const float*)d_in[10];
  const float* W2b = (const float*)d_in[11];
  const float* U2b = (const float*)d_in[12];
  const float* b2b = (const float*)d_in[13];
  float* out = (float*)d_out;

  char* ws = (char*)d_ws;
  // ws layout (bytes), total ~208.6 MB:
  //   xz    bf16 [32768][2048]  @ 0           (134,217,728)
  //   l1    bf16 [32768][1024]  @ 134,217,728 ( 67,108,864)
  //   Ut    fp32 4x[2048][512]  @ 201,326,592 ( 16,777,216)
  //   hbufT fp32 [2][512][64]   @ 218,103,808 (    262,144)
  //   bar                       @ 218,365,952
  unsigned short* xz  = (unsigned short*)(ws + 0ull);
  unsigned short* l1  = (unsigned short*)(ws + 134217728ull);
  float* Ut1f = (float*)(ws + 201326592ull);
  float* Ut1b = Ut1f + 1048576;
  float* Ut2f = Ut1b + 1048576;
  float* Ut2b = Ut2f + 1048576;
  float* hbufT = (float*)(ws + 218103808ull);
  unsigned* bar  = (unsigned*)(ws + 218365952ull);

  transpose_u<<<1024, 256, 0, stream>>>(U1f, Ut1f);
  transpose_u<<<1024, 256, 0, stream>>>(U1b, Ut1b);
  transpose_u<<<1024, 256, 0, stream>>>(U2f, Ut2f);
  transpose_u<<<1024, 256, 0, stream>>>(U2b, Ut2b);
  hipMemsetAsync(bar, 0, 1024, stream);

  // ---- layer 1 forward ----
  gemm_bias<false><<<8192, 256, 0, stream>>>(emb, W1f, b1f, xz, 512, ids);
  lstm_dir_k<<<NBLK_LSTM, 256, 0, stream>>>(xz, Ut1f, nullptr, l1 + 0, hbufT,
                                            nullptr, nullptr, 0, bar);
  // ---- layer 1 backward ----
  gemm_bias<false><<<8192, 256, 0, stream>>>(emb, W1b, b1b, xz, 512, ids);
  lstm_dir_k<<<NBLK_LSTM, 256, 0, stream>>>(xz, Ut1b, nullptr, l1 + 512, hbufT,
                                            nullptr, nullptr, 1, bar);
  // ---- layer 2 forward ----
  gemm_bias<true><<<8192, 256, 0, stream>>>(l1, W2f, b2f, xz, 1024, nullptr);
  lstm_dir_k<<<NBLK_LSTM, 256, 0, stream>>>(xz, Ut2f, out, nullptr, hbufT,
                                            out + 33554432, out + 33619968, 0, bar);
  // ---- layer 2 backward ----
  gemm_bias<true><<<8192, 256, 0, stream>>>(l1, W2b, b2b, xz, 1024, nullptr);
  lstm_dir_k<<<NBLK_LSTM, 256, 0, stream>>>(xz, Ut2b, out + 512, nullptr, hbufT,
                                            out + 33554432 + 512, out + 33619968 + 512, 1, bar);
}

// Round 4
// 18000.198 us; speedup vs baseline: 7.8142x; 4.1701x over previous
//
#include <hip/hip_runtime.h>
#include <math.h>

// ---------------------------------------------------------------------------
// Encoder: 2-layer bidirectional LSTM, B=64, T=512, E=H=512, fp32 in/out.
// Round 4: recurrence cross-block traffic moved to IF-coherence (sc0 sc1
// bypass ops) + fully RELAXED monotonic barrier -> no per-step L2
// writeback/invalidate storms (round-3's 33-95 us/step stall).
// ---------------------------------------------------------------------------

#define NBLK_LSTM 256

__device__ __forceinline__ float bf2f(unsigned short u) {
  return __uint_as_float(((unsigned)u) << 16);
}
__device__ __forceinline__ unsigned short f2bf(float f) {
  unsigned u = __float_as_uint(f);
  unsigned r = (u + 0x7FFFu + ((u >> 16) & 1u)) >> 16;
  return (unsigned short)r;
}
__device__ __forceinline__ float sigmoidf_(float x) {
  return 1.0f / (1.0f + expf(-x));
}

// ---------------- U transpose: Ut[col][k] = U[k][col] (fp32) ----------------
__global__ __launch_bounds__(256) void transpose_u(const float* __restrict__ U,
                                                   float* __restrict__ Ut) {
  __shared__ float tile[32][33];
  int kt = blockIdx.x & 15;
  int ct = blockIdx.x >> 4;
  int k0 = kt * 32, c0 = ct * 32;
  int tx = threadIdx.x & 31, ty = threadIdx.x >> 5;
#pragma unroll
  for (int i = 0; i < 32; i += 8)
    tile[ty + i][tx] = U[(size_t)(k0 + ty + i) * 2048 + c0 + tx];
  __syncthreads();
#pragma unroll
  for (int i = 0; i < 32; i += 8)
    Ut[(size_t)(c0 + ty + i) * 512 + k0 + tx] = tile[tx][ty + i];
}

// ---------------- GEMM: C_bf16[M,2048] = A[M,K] @ W[K,2048] + bias ----------
template <bool ABF16>
__global__ __launch_bounds__(256) void gemm_bias(const void* __restrict__ Av,
                                                 const float* __restrict__ W,
                                                 const float* __restrict__ bias,
                                                 unsigned short* __restrict__ C,
                                                 int K,
                                                 const int* __restrict__ gather) {
  __shared__ float As[16][132];
  __shared__ float Bs[16][68];
  const int bm = blockIdx.x & 255;
  const int bn = blockIdx.x >> 8;
  const int m0 = bm * 128, n0 = bn * 64;
  const int tid = threadIdx.x;
  const int tx = tid & 15, ty = tid >> 4;

  float acc[8][4];
#pragma unroll
  for (int r = 0; r < 8; r++)
#pragma unroll
    for (int q = 0; q < 4; q++) acc[r][q] = 0.0f;

  for (int k0 = 0; k0 < K; k0 += 16) {
#pragma unroll
    for (int s = 0; s < 2; s++) {
      int slot = tid + s * 256;
      int row = slot >> 2;
      int f4 = (slot & 3) * 4;
      if (ABF16) {
        const unsigned short* A = (const unsigned short*)Av;
        size_t abase = (size_t)(m0 + row) * K;
        ushort4 v = *(const ushort4*)&A[abase + k0 + f4];
        As[f4 + 0][row] = bf2f(v.x);
        As[f4 + 1][row] = bf2f(v.y);
        As[f4 + 2][row] = bf2f(v.z);
        As[f4 + 3][row] = bf2f(v.w);
      } else {
        const float* A = (const float*)Av;
        size_t abase = gather ? ((size_t)gather[m0 + row] * 512)
                              : ((size_t)(m0 + row) * K);
        float4 v = *(const float4*)&A[abase + k0 + f4];
        As[f4 + 0][row] = v.x;
        As[f4 + 1][row] = v.y;
        As[f4 + 2][row] = v.z;
        As[f4 + 3][row] = v.w;
      }
    }
    {
      int kr = tid >> 4;
      int nf = (tid & 15) * 4;
      *(float4*)&Bs[kr][nf] = *(const float4*)&W[(size_t)(k0 + kr) * 2048 + n0 + nf];
    }
    __syncthreads();
#pragma unroll
    for (int k = 0; k < 16; k++) {
      float4 a0 = *(const float4*)&As[k][ty * 8];
      float4 a1 = *(const float4*)&As[k][ty * 8 + 4];
      float4 b0 = *(const float4*)&Bs[k][tx * 4];
      float av[8] = {a0.x, a0.y, a0.z, a0.w, a1.x, a1.y, a1.z, a1.w};
      float bv[4] = {b0.x, b0.y, b0.z, b0.w};
#pragma unroll
      for (int r = 0; r < 8; r++)
#pragma unroll
        for (int q = 0; q < 4; q++)
          acc[r][q] = fmaf(av[r], bv[q], acc[r][q]);
    }
    __syncthreads();
  }

  float4 bb = *(const float4*)&bias[n0 + tx * 4];
#pragma unroll
  for (int r = 0; r < 8; r++) {
    ushort4 o;
    o.x = f2bf(acc[r][0] + bb.x);
    o.y = f2bf(acc[r][1] + bb.y);
    o.z = f2bf(acc[r][2] + bb.z);
    o.w = f2bf(acc[r][3] + bb.w);
    *(ushort4*)&C[(size_t)(m0 + ty * 8 + r) * 2048 + n0 + tx * 4] = o;
  }
}

// ---------------- recurrence (one direction) --------------------------------
// 256 blocks x 256 threads, 1 block/CU. Block owns j = {2*bid, 2*bid+1}.
// h exchange via sc0 sc1 (IF-coherent) ops; relaxed monotonic barrier.
__global__ __launch_bounds__(256, 1) void lstm_dir_k(
    const unsigned short* __restrict__ xz,   // bf16 [64*512][2048]
    const float* __restrict__ Ut,            // fp32 [2048 cols][512 k]
    float* __restrict__ hsF,                 // fp32 out (stride 1024) or null
    unsigned short* __restrict__ hsB16,      // bf16 out (stride 1024) or null
    float* __restrict__ hbufT,               // fp32 [2][512 j][64 b]
    float* __restrict__ stateh, float* __restrict__ statec,
    int reverse, unsigned* __restrict__ bar) {
  __shared__ float u_lds[32][16][12];   // [kin][seg][c(8)+pad] : 24 KB
  __shared__ float p_lds[4][64 * 9];    // [wave][b*9 + c]      : 9.2 KB

  const int tid = threadIdx.x;
  const int bid = blockIdx.x;
  const int jbase = bid * 2;

  // stage U slice (8 cols: c=(g,jl) -> col g*512 + jbase + jl)
  {
    int c = tid >> 5;
    int k0 = (tid & 31) * 16;
    const int g = c >> 1, jl = c & 1;
    const float* src = Ut + ((size_t)(g * 512 + jbase + jl)) * 512 + k0;
#pragma unroll
    for (int kk = 0; kk < 16; kk++) {
      int k = k0 + kk;
      u_lds[k & 31][k >> 5][c] = src[kk];
    }
  }
  __syncthreads();

  const int seg = tid >> 4;        // 0..15
  const int bg  = tid & 15;
  const int b0  = bg * 4;
  const int bu  = tid >> 1;        // update-phase batch (tid<128)
  const int jl  = tid & 1;
  const int j   = jbase + jl;

  unsigned* leaf = bar + ((bid & 7) << 5);   // 8 leaves, 128B apart
  unsigned* root = bar + 288;
  unsigned* gen  = bar + 320;

  const unsigned short* xzb = xz + (size_t)bu * (512 * 2048) + j;

  float creg = 0.0f;
  float zx0 = 0, zx1 = 0, zx2 = 0, zx3 = 0;
  if (tid < 128) {
    const unsigned short* p = xzb + (size_t)(reverse ? 511 : 0) * 2048;
    zx0 = bf2f(p[0]); zx1 = bf2f(p[512]); zx2 = bf2f(p[1024]); zx3 = bf2f(p[1536]);
  }

  for (int s = 0; s < 512; s++) {
    const int tt = reverse ? (511 - s) : s;

    if (s > 0) {
      float4 hreg[32];
      const float* hrow = hbufT + (size_t)(s & 1) * 32768 + seg * 2048 + b0;
#pragma unroll
      for (int i = 0; i < 32; i++) {
        const float* p = hrow + i * 64;
        asm volatile("global_load_dwordx4 %0, %1, off sc0 sc1"
                     : "=v"(hreg[i]) : "v"(p) : "memory");
      }
      float acc[4][8];
#pragma unroll
      for (int bi = 0; bi < 4; bi++)
#pragma unroll
        for (int c = 0; c < 8; c++) acc[bi][c] = 0.0f;

      asm volatile("s_waitcnt vmcnt(16)" ::: "memory");
      __builtin_amdgcn_sched_barrier(0);
#pragma unroll
      for (int i = 0; i < 16; i++) {
        float4 h4 = hreg[i];
        float4 ua = *(const float4*)&u_lds[i][seg][0];
        float4 ub = *(const float4*)&u_lds[i][seg][4];
        float hv[4] = {h4.x, h4.y, h4.z, h4.w};
        float uv[8] = {ua.x, ua.y, ua.z, ua.w, ub.x, ub.y, ub.z, ub.w};
#pragma unroll
        for (int bi = 0; bi < 4; bi++)
#pragma unroll
          for (int c = 0; c < 8; c++)
            acc[bi][c] = fmaf(hv[bi], uv[c], acc[bi][c]);
      }
      asm volatile("s_waitcnt vmcnt(0)" ::: "memory");
      __builtin_amdgcn_sched_barrier(0);
#pragma unroll
      for (int i = 16; i < 32; i++) {
        float4 h4 = hreg[i];
        float4 ua = *(const float4*)&u_lds[i][seg][0];
        float4 ub = *(const float4*)&u_lds[i][seg][4];
        float hv[4] = {h4.x, h4.y, h4.z, h4.w};
        float uv[8] = {ua.x, ua.y, ua.z, ua.w, ub.x, ub.y, ub.z, ub.w};
#pragma unroll
        for (int bi = 0; bi < 4; bi++)
#pragma unroll
          for (int c = 0; c < 8; c++)
            acc[bi][c] = fmaf(hv[bi], uv[c], acc[bi][c]);
      }
#pragma unroll
      for (int bi = 0; bi < 4; bi++)
#pragma unroll
        for (int c = 0; c < 8; c++) {
          float v = acc[bi][c];
          v += __shfl_xor(v, 16);
          v += __shfl_xor(v, 32);
          acc[bi][c] = v;
        }
      if ((tid & 48) == 0) {
        const int w = tid >> 6;
#pragma unroll
        for (int bi = 0; bi < 4; bi++)
#pragma unroll
          for (int c = 0; c < 8; c++)
            p_lds[w][(b0 + bi) * 9 + c] = acc[bi][c];
      }
    }
    __syncthreads();

    if (tid < 128) {
      float z0 = zx0, z1 = zx1, z2 = zx2, z3 = zx3;
      if (s > 0) {
#pragma unroll
        for (int w = 0; w < 4; w++) {
          const float* p = &p_lds[w][bu * 9 + jl];
          z0 += p[0];
          z1 += p[2];
          z2 += p[4];
          z3 += p[6];
        }
      }
      float si = sigmoidf_(z0);
      float sf = sigmoidf_(z1);
      float tg = tanhf(z2);
      float so = sigmoidf_(z3);
      creg = fmaf(sf, creg, si * tg);
      float h = so * tanhf(creg);

      float* hp = hbufT + (size_t)((s & 1) ^ 1) * 32768 + (size_t)j * 64 + bu;
      asm volatile("global_store_dword %0, %1, off sc0 sc1"
                   :: "v"(hp), "v"(h) : "memory");

      if (s < 511) {
        // hs store + next-xz prefetch happen under the barrier below
        zx0 = h;  // stash h in zx0 temporarily? no -- keep h separate
        zx0 = zx0; // (no-op; h handled below)
      }
      // output stores done in barrier window / at final step
      if (s == 511) {
        if (hsB16) hsB16[((size_t)bu * 512 + tt) * 1024 + j] = f2bf(h);
        else       hsF [((size_t)bu * 512 + tt) * 1024 + j] = h;
        if (stateh != nullptr) {
          stateh[bu * 1024 + j] = h;
          statec[bu * 1024 + j] = creg;
        }
      } else {
        // store hs now (plain, consumed only after dispatch end)
        if (hsB16) hsB16[((size_t)bu * 512 + tt) * 1024 + j] = f2bf(h);
        else       hsF [((size_t)bu * 512 + tt) * 1024 + j] = h;
      }
    }

    if (s < 511) {
      asm volatile("s_waitcnt vmcnt(0)" ::: "memory");
      __syncthreads();
      if (tid == 0) {
        unsigned a = __hip_atomic_fetch_add(leaf, 1u, __ATOMIC_RELAXED,
                                            __HIP_MEMORY_SCOPE_AGENT) + 1u;
        if (a == 32u * (unsigned)(s + 1)) {
          unsigned r = __hip_atomic_fetch_add(root, 1u, __ATOMIC_RELAXED,
                                              __HIP_MEMORY_SCOPE_AGENT) + 1u;
          if (r == 8u * (unsigned)(s + 1))
            __hip_atomic_fetch_add(gen, 1u, __ATOMIC_RELAXED,
                                   __HIP_MEMORY_SCOPE_AGENT);
        }
      }
      if (tid < 128) {
        const int tn = reverse ? (511 - (s + 1)) : (s + 1);
        const unsigned short* p = xzb + (size_t)tn * 2048;
        zx0 = bf2f(p[0]); zx1 = bf2f(p[512]);
        zx2 = bf2f(p[1024]); zx3 = bf2f(p[1536]);
      }
      if (tid == 0) {
        while (__hip_atomic_load(gen, __ATOMIC_RELAXED,
                                 __HIP_MEMORY_SCOPE_AGENT) <= (unsigned)s)
          __builtin_amdgcn_s_sleep(1);
      }
      __syncthreads();
    }
  }
}

// ---------------------------------------------------------------------------
extern "C" void kernel_launch(void* const* d_in, const int* in_sizes, int n_in,
                              void* d_out, int out_size, void* d_ws, size_t ws_size,
                              hipStream_t stream) {
  const int*   ids = (const int*)d_in[0];
  const float* emb = (const float*)d_in[1];
  const float* W1f = (const float*)d_in[2];
  const float* U1f = (const float*)d_in[3];
  const float* b1f = (const float*)d_in[4];
  const float* W1b = (const float*)d_in[5];
  const float* U1b = (const float*)d_in[6];
  const float* b1b = (const float*)d_in[7];
  const float* W2f = (const float*)d_in[8];
  const float* U2f = (const float*)d_in[9];
  const float* b2f = (const float*)d_in[10];
  const float* W2b = (const float*)d_in[11];
  const float* U2b = (const float*)d_in[12];
  const float* b2b = (const float*)d_in[13];
  float* out = (float*)d_out;

  char* ws = (char*)d_ws;
  unsigned short* xz  = (unsigned short*)(ws + 0ull);
  unsigned short* l1  = (unsigned short*)(ws + 134217728ull);
  float* Ut1f = (float*)(ws + 201326592ull);
  float* Ut1b = Ut1f + 1048576;
  float* Ut2f = Ut1b + 1048576;
  float* Ut2b = Ut2f + 1048576;
  float* hbufT = (float*)(ws + 218103808ull);
  unsigned* bar  = (unsigned*)(ws + 218365952ull);

  transpose_u<<<1024, 256, 0, stream>>>(U1f, Ut1f);
  transpose_u<<<1024, 256, 0, stream>>>(U1b, Ut1b);
  transpose_u<<<1024, 256, 0, stream>>>(U2f, Ut2f);
  transpose_u<<<1024, 256, 0, stream>>>(U2b, Ut2b);

  // ---- layer 1 forward ----
  gemm_bias<false><<<8192, 256, 0, stream>>>(emb, W1f, b1f, xz, 512, ids);
  hipMemsetAsync(bar, 0, 4096, stream);
  lstm_dir_k<<<NBLK_LSTM, 256, 0, stream>>>(xz, Ut1f, nullptr, l1 + 0, hbufT,
                                            nullptr, nullptr, 0, bar);
  // ---- layer 1 backward ----
  gemm_bias<false><<<8192, 256, 0, stream>>>(emb, W1b, b1b, xz, 512, ids);
  hipMemsetAsync(bar, 0, 4096, stream);
  lstm_dir_k<<<NBLK_LSTM, 256, 0, stream>>>(xz, Ut1b, nullptr, l1 + 512, hbufT,
                                            nullptr, nullptr, 1, bar);
  // ---- layer 2 forward ----
  gemm_bias<true><<<8192, 256, 0, stream>>>(l1, W2f, b2f, xz, 1024, nullptr);
  hipMemsetAsync(bar, 0, 4096, stream);
  lstm_dir_k<<<NBLK_LSTM, 256, 0, stream>>>(xz, Ut2f, out, nullptr, hbufT,
                                            out + 33554432, out + 33619968, 0, bar);
  // ---- layer 2 backward ----
  gemm_bias<true><<<8192, 256, 0, stream>>>(l1, W2b, b2b, xz, 1024, nullptr);
  hipMemsetAsync(bar, 0, 4096, stream);
  lstm_dir_k<<<NBLK_LSTM, 256, 0, stream>>>(xz, Ut2b, out + 512, nullptr, hbufT,
                                            out + 33554432 + 512, out + 33619968 + 512, 1, bar);
}

// Round 5
// 16099.507 us; speedup vs baseline: 8.7368x; 1.1181x over previous
//
#include <hip/hip_runtime.h>
#include <math.h>

// ---------------------------------------------------------------------------
// Encoder: 2-layer bidirectional LSTM, B=64, T=512, E=H=512, fp32 in/out.
// Round 5: fuse fwd+bwd recurrence into ONE persistent dispatch per layer
// (both directions per block, one barrier per epoch) -> latency chain paid
// once for 2x work. Runtime ws_size branch: BIG (272.5 MB) fused path,
// else exact round-4 fallback.
// ---------------------------------------------------------------------------

#define NBLK_LSTM 256

__device__ __forceinline__ float bf2f(unsigned short u) {
  return __uint_as_float(((unsigned)u) << 16);
}
__device__ __forceinline__ unsigned short f2bf(float f) {
  unsigned u = __float_as_uint(f);
  unsigned r = (u + 0x7FFFu + ((u >> 16) & 1u)) >> 16;
  return (unsigned short)r;
}
__device__ __forceinline__ float sigmoidf_(float x) {
  return 1.0f / (1.0f + expf(-x));
}

// ---------------- U transpose: Ut[col][k] = U[k][col] (fp32) ----------------
__global__ __launch_bounds__(256) void transpose_u(const float* __restrict__ U,
                                                   float* __restrict__ Ut) {
  __shared__ float tile[32][33];
  int kt = blockIdx.x & 15;
  int ct = blockIdx.x >> 4;
  int k0 = kt * 32, c0 = ct * 32;
  int tx = threadIdx.x & 31, ty = threadIdx.x >> 5;
#pragma unroll
  for (int i = 0; i < 32; i += 8)
    tile[ty + i][tx] = U[(size_t)(k0 + ty + i) * 2048 + c0 + tx];
  __syncthreads();
#pragma unroll
  for (int i = 0; i < 32; i += 8)
    Ut[(size_t)(c0 + ty + i) * 512 + k0 + tx] = tile[tx][ty + i];
}

// ---------------- GEMM: C_bf16[M,2048] = A[M,K] @ W[K,2048] + bias ----------
template <bool ABF16>
__global__ __launch_bounds__(256) void gemm_bias(const void* __restrict__ Av,
                                                 const float* __restrict__ W,
                                                 const float* __restrict__ bias,
                                                 unsigned short* __restrict__ C,
                                                 int K,
                                                 const int* __restrict__ gather) {
  __shared__ float As[16][132];
  __shared__ float Bs[16][68];
  const int bm = blockIdx.x & 255;
  const int bn = blockIdx.x >> 8;
  const int m0 = bm * 128, n0 = bn * 64;
  const int tid = threadIdx.x;
  const int tx = tid & 15, ty = tid >> 4;

  float acc[8][4];
#pragma unroll
  for (int r = 0; r < 8; r++)
#pragma unroll
    for (int q = 0; q < 4; q++) acc[r][q] = 0.0f;

  for (int k0 = 0; k0 < K; k0 += 16) {
#pragma unroll
    for (int s = 0; s < 2; s++) {
      int slot = tid + s * 256;
      int row = slot >> 2;
      int f4 = (slot & 3) * 4;
      if (ABF16) {
        const unsigned short* A = (const unsigned short*)Av;
        size_t abase = (size_t)(m0 + row) * K;
        ushort4 v = *(const ushort4*)&A[abase + k0 + f4];
        As[f4 + 0][row] = bf2f(v.x);
        As[f4 + 1][row] = bf2f(v.y);
        As[f4 + 2][row] = bf2f(v.z);
        As[f4 + 3][row] = bf2f(v.w);
      } else {
        const float* A = (const float*)Av;
        size_t abase = gather ? ((size_t)gather[m0 + row] * 512)
                              : ((size_t)(m0 + row) * K);
        float4 v = *(const float4*)&A[abase + k0 + f4];
        As[f4 + 0][row] = v.x;
        As[f4 + 1][row] = v.y;
        As[f4 + 2][row] = v.z;
        As[f4 + 3][row] = v.w;
      }
    }
    {
      int kr = tid >> 4;
      int nf = (tid & 15) * 4;
      *(float4*)&Bs[kr][nf] = *(const float4*)&W[(size_t)(k0 + kr) * 2048 + n0 + nf];
    }
    __syncthreads();
#pragma unroll
    for (int k = 0; k < 16; k++) {
      float4 a0 = *(const float4*)&As[k][ty * 8];
      float4 a1 = *(const float4*)&As[k][ty * 8 + 4];
      float4 b0 = *(const float4*)&Bs[k][tx * 4];
      float av[8] = {a0.x, a0.y, a0.z, a0.w, a1.x, a1.y, a1.z, a1.w};
      float bv[4] = {b0.x, b0.y, b0.z, b0.w};
#pragma unroll
      for (int r = 0; r < 8; r++)
#pragma unroll
        for (int q = 0; q < 4; q++)
          acc[r][q] = fmaf(av[r], bv[q], acc[r][q]);
    }
    __syncthreads();
  }

  float4 bb = *(const float4*)&bias[n0 + tx * 4];
#pragma unroll
  for (int r = 0; r < 8; r++) {
    ushort4 o;
    o.x = f2bf(acc[r][0] + bb.x);
    o.y = f2bf(acc[r][1] + bb.y);
    o.z = f2bf(acc[r][2] + bb.z);
    o.w = f2bf(acc[r][3] + bb.w);
    *(ushort4*)&C[(size_t)(m0 + ty * 8 + r) * 2048 + n0 + tx * 4] = o;
  }
}

// ============================================================================
// FUSED recurrence: both directions in one dispatch. 256 blocks x 256 thr.
// Block owns j = {2*bid, 2*bid+1} for fwd AND bwd (16 U-cols in LDS).
// Per epoch: compute fwd partials, then bwd partials (hreg/acc reused);
// update phase: tid<128 -> fwd, tid>=128 -> bwd. One barrier per epoch.
// hbuf: fp32 [dir][buf][512 j][64 b].
// ============================================================================
__global__ __launch_bounds__(256, 1) void lstm_fused(
    const unsigned short* __restrict__ xzF,  // bf16 [64*512][2048]
    const unsigned short* __restrict__ xzB,
    const float* __restrict__ UtF,           // fp32 [2048 cols][512 k]
    const float* __restrict__ UtB,
    float* __restrict__ outF32,              // fp32 out stride 1024 (or null)
    unsigned short* __restrict__ outB16,     // bf16 out stride 1024 (or null)
    float* __restrict__ hbuf,                // fp32 [2][2][512][64]
    float* __restrict__ stateh, float* __restrict__ statec,
    unsigned* __restrict__ bar) {
  __shared__ float u_lds[2][32][16][12];   // 48 KB
  __shared__ float p_lds[2][4][64 * 9];    // 18.4 KB

  const int tid = threadIdx.x;
  const int bid = blockIdx.x;
  const int jbase = bid * 2;

  // stage U for both directions (8 cols each)
#pragma unroll
  for (int d = 0; d < 2; d++) {
    const float* Ut = d ? UtB : UtF;
    int c = tid >> 5;
    int k0 = (tid & 31) * 16;
    const int g = c >> 1, jl = c & 1;
    const float* src = Ut + ((size_t)(g * 512 + jbase + jl)) * 512 + k0;
#pragma unroll
    for (int kk = 0; kk < 16; kk++) {
      int k = k0 + kk;
      u_lds[d][k & 31][k >> 5][c] = src[kk];
    }
  }
  __syncthreads();

  const int seg = tid >> 4;          // 0..15
  const int bg  = tid & 15;
  const int b0  = bg * 4;

  // update-phase identity (all 256 threads)
  const int udir = tid >> 7;         // 0 fwd, 1 bwd
  const int bu   = (tid & 127) >> 1;
  const int jl   = tid & 1;
  const int j    = jbase + jl;

  unsigned* leaf = bar + ((bid & 7) << 5);
  unsigned* root = bar + 288;
  unsigned* gen  = bar + 320;

  const unsigned short* xzbase =
      (udir ? xzB : xzF) + (size_t)bu * (512 * 2048) + j;

  float creg = 0.0f;
  float zx0, zx1, zx2, zx3;
  {
    const unsigned short* p = xzbase + (size_t)(udir ? 511 : 0) * 2048;
    zx0 = bf2f(p[0]); zx1 = bf2f(p[512]);
    zx2 = bf2f(p[1024]); zx3 = bf2f(p[1536]);
  }

  for (int s = 0; s < 512; s++) {
    if (s > 0) {
#pragma unroll
      for (int d = 0; d < 2; d++) {
        float4 hreg[32];
        const float* hrow =
            hbuf + (size_t)d * 65536 + (size_t)(s & 1) * 32768 + seg * 2048 + b0;
#pragma unroll
        for (int i = 0; i < 32; i++) {
          const float* p = hrow + i * 64;
          asm volatile("global_load_dwordx4 %0, %1, off sc0 sc1"
                       : "=v"(hreg[i]) : "v"(p) : "memory");
        }
        float acc[4][8];
#pragma unroll
        for (int bi = 0; bi < 4; bi++)
#pragma unroll
          for (int c = 0; c < 8; c++) acc[bi][c] = 0.0f;

        asm volatile("s_waitcnt vmcnt(16)" ::: "memory");
        __builtin_amdgcn_sched_barrier(0);
#pragma unroll
        for (int i = 0; i < 16; i++) {
          float4 h4 = hreg[i];
          float4 ua = *(const float4*)&u_lds[d][i][seg][0];
          float4 ub = *(const float4*)&u_lds[d][i][seg][4];
          float hv[4] = {h4.x, h4.y, h4.z, h4.w};
          float uv[8] = {ua.x, ua.y, ua.z, ua.w, ub.x, ub.y, ub.z, ub.w};
#pragma unroll
          for (int bi = 0; bi < 4; bi++)
#pragma unroll
            for (int c = 0; c < 8; c++)
              acc[bi][c] = fmaf(hv[bi], uv[c], acc[bi][c]);
        }
        asm volatile("s_waitcnt vmcnt(0)" ::: "memory");
        __builtin_amdgcn_sched_barrier(0);
#pragma unroll
        for (int i = 16; i < 32; i++) {
          float4 h4 = hreg[i];
          float4 ua = *(const float4*)&u_lds[d][i][seg][0];
          float4 ub = *(const float4*)&u_lds[d][i][seg][4];
          float hv[4] = {h4.x, h4.y, h4.z, h4.w};
          float uv[8] = {ua.x, ua.y, ua.z, ua.w, ub.x, ub.y, ub.z, ub.w};
#pragma unroll
          for (int bi = 0; bi < 4; bi++)
#pragma unroll
            for (int c = 0; c < 8; c++)
              acc[bi][c] = fmaf(hv[bi], uv[c], acc[bi][c]);
        }
#pragma unroll
        for (int bi = 0; bi < 4; bi++)
#pragma unroll
          for (int c = 0; c < 8; c++) {
            float v = acc[bi][c];
            v += __shfl_xor(v, 16);
            v += __shfl_xor(v, 32);
            acc[bi][c] = v;
          }
        if ((tid & 48) == 0) {
          const int w = tid >> 6;
#pragma unroll
          for (int bi = 0; bi < 4; bi++)
#pragma unroll
            for (int c = 0; c < 8; c++)
              p_lds[d][w][(b0 + bi) * 9 + c] = acc[bi][c];
        }
      }
    }
    __syncthreads();

    // ---- update: all 256 threads (128 fwd + 128 bwd) ----
    {
      float z0 = zx0, z1 = zx1, z2 = zx2, z3 = zx3;
      if (s > 0) {
#pragma unroll
        for (int w = 0; w < 4; w++) {
          const float* p = &p_lds[udir][w][bu * 9 + jl];
          z0 += p[0];
          z1 += p[2];
          z2 += p[4];
          z3 += p[6];
        }
      }
      float si = sigmoidf_(z0);
      float sf = sigmoidf_(z1);
      float tg = tanhf(z2);
      float so = sigmoidf_(z3);
      creg = fmaf(sf, creg, si * tg);
      float h = so * tanhf(creg);

      float* hp = hbuf + (size_t)udir * 65536 +
                  (size_t)((s & 1) ^ 1) * 32768 + (size_t)j * 64 + bu;
      asm volatile("global_store_dword %0, %1, off sc0 sc1"
                   :: "v"(hp), "v"(h) : "memory");

      const int tt = udir ? (511 - s) : s;
      const int col = udir * 512 + j;
      if (outB16) {
        outB16[((size_t)bu * 512 + tt) * 1024 + col] = f2bf(h);
      } else {
        outF32[((size_t)bu * 512 + tt) * 1024 + col] = h;
        if (s == 511 && stateh != nullptr) {
          stateh[bu * 1024 + col] = h;
          statec[bu * 1024 + col] = creg;
        }
      }
    }

    if (s < 511) {
      asm volatile("s_waitcnt vmcnt(0)" ::: "memory");
      __syncthreads();
      if (tid == 0) {
        unsigned a = __hip_atomic_fetch_add(leaf, 1u, __ATOMIC_RELAXED,
                                            __HIP_MEMORY_SCOPE_AGENT) + 1u;
        if (a == 32u * (unsigned)(s + 1)) {
          unsigned r = __hip_atomic_fetch_add(root, 1u, __ATOMIC_RELAXED,
                                              __HIP_MEMORY_SCOPE_AGENT) + 1u;
          if (r == 8u * (unsigned)(s + 1))
            __hip_atomic_fetch_add(gen, 1u, __ATOMIC_RELAXED,
                                   __HIP_MEMORY_SCOPE_AGENT);
        }
      }
      {
        const int tn = udir ? (510 - s) : (s + 1);
        const unsigned short* p = xzbase + (size_t)tn * 2048;
        zx0 = bf2f(p[0]); zx1 = bf2f(p[512]);
        zx2 = bf2f(p[1024]); zx3 = bf2f(p[1536]);
      }
      if (tid == 0) {
        while (__hip_atomic_load(gen, __ATOMIC_RELAXED,
                                 __HIP_MEMORY_SCOPE_AGENT) <= (unsigned)s)
          __builtin_amdgcn_s_sleep(1);
      }
      __syncthreads();
    }
  }
}

// ============================================================================
// Round-4 fallback recurrence (one direction) — unchanged, known-good.
// ============================================================================
__global__ __launch_bounds__(256, 1) void lstm_dir_k(
    const unsigned short* __restrict__ xz,
    const float* __restrict__ Ut,
    float* __restrict__ hsF,
    unsigned short* __restrict__ hsB16,
    float* __restrict__ hbufT,
    float* __restrict__ stateh, float* __restrict__ statec,
    int reverse, unsigned* __restrict__ bar) {
  __shared__ float u_lds[32][16][12];
  __shared__ float p_lds[4][64 * 9];

  const int tid = threadIdx.x;
  const int bid = blockIdx.x;
  const int jbase = bid * 2;

  {
    int c = tid >> 5;
    int k0 = (tid & 31) * 16;
    const int g = c >> 1, jl = c & 1;
    const float* src = Ut + ((size_t)(g * 512 + jbase + jl)) * 512 + k0;
#pragma unroll
    for (int kk = 0; kk < 16; kk++) {
      int k = k0 + kk;
      u_lds[k & 31][k >> 5][c] = src[kk];
    }
  }
  __syncthreads();

  const int seg = tid >> 4;
  const int bg  = tid & 15;
  const int b0  = bg * 4;
  const int bu  = tid >> 1;
  const int jl  = tid & 1;
  const int j   = jbase + jl;

  unsigned* leaf = bar + ((bid & 7) << 5);
  unsigned* root = bar + 288;
  unsigned* gen  = bar + 320;

  const unsigned short* xzb = xz + (size_t)bu * (512 * 2048) + j;

  float creg = 0.0f;
  float zx0 = 0, zx1 = 0, zx2 = 0, zx3 = 0;
  if (tid < 128) {
    const unsigned short* p = xzb + (size_t)(reverse ? 511 : 0) * 2048;
    zx0 = bf2f(p[0]); zx1 = bf2f(p[512]); zx2 = bf2f(p[1024]); zx3 = bf2f(p[1536]);
  }

  for (int s = 0; s < 512; s++) {
    const int tt = reverse ? (511 - s) : s;

    if (s > 0) {
      float4 hreg[32];
      const float* hrow = hbufT + (size_t)(s & 1) * 32768 + seg * 2048 + b0;
#pragma unroll
      for (int i = 0; i < 32; i++) {
        const float* p = hrow + i * 64;
        asm volatile("global_load_dwordx4 %0, %1, off sc0 sc1"
                     : "=v"(hreg[i]) : "v"(p) : "memory");
      }
      float acc[4][8];
#pragma unroll
      for (int bi = 0; bi < 4; bi++)
#pragma unroll
        for (int c = 0; c < 8; c++) acc[bi][c] = 0.0f;

      asm volatile("s_waitcnt vmcnt(16)" ::: "memory");
      __builtin_amdgcn_sched_barrier(0);
#pragma unroll
      for (int i = 0; i < 16; i++) {
        float4 h4 = hreg[i];
        float4 ua = *(const float4*)&u_lds[i][seg][0];
        float4 ub = *(const float4*)&u_lds[i][seg][4];
        float hv[4] = {h4.x, h4.y, h4.z, h4.w};
        float uv[8] = {ua.x, ua.y, ua.z, ua.w, ub.x, ub.y, ub.z, ub.w};
#pragma unroll
        for (int bi = 0; bi < 4; bi++)
#pragma unroll
          for (int c = 0; c < 8; c++)
            acc[bi][c] = fmaf(hv[bi], uv[c], acc[bi][c]);
      }
      asm volatile("s_waitcnt vmcnt(0)" ::: "memory");
      __builtin_amdgcn_sched_barrier(0);
#pragma unroll
      for (int i = 16; i < 32; i++) {
        float4 h4 = hreg[i];
        float4 ua = *(const float4*)&u_lds[i][seg][0];
        float4 ub = *(const float4*)&u_lds[i][seg][4];
        float hv[4] = {h4.x, h4.y, h4.z, h4.w};
        float uv[8] = {ua.x, ua.y, ua.z, ua.w, ub.x, ub.y, ub.z, ub.w};
#pragma unroll
        for (int bi = 0; bi < 4; bi++)
#pragma unroll
          for (int c = 0; c < 8; c++)
            acc[bi][c] = fmaf(hv[bi], uv[c], acc[bi][c]);
      }
#pragma unroll
      for (int bi = 0; bi < 4; bi++)
#pragma unroll
        for (int c = 0; c < 8; c++) {
          float v = acc[bi][c];
          v += __shfl_xor(v, 16);
          v += __shfl_xor(v, 32);
          acc[bi][c] = v;
        }
      if ((tid & 48) == 0) {
        const int w = tid >> 6;
#pragma unroll
        for (int bi = 0; bi < 4; bi++)
#pragma unroll
          for (int c = 0; c < 8; c++)
            p_lds[w][(b0 + bi) * 9 + c] = acc[bi][c];
      }
    }
    __syncthreads();

    if (tid < 128) {
      float z0 = zx0, z1 = zx1, z2 = zx2, z3 = zx3;
      if (s > 0) {
#pragma unroll
        for (int w = 0; w < 4; w++) {
          const float* p = &p_lds[w][bu * 9 + jl];
          z0 += p[0];
          z1 += p[2];
          z2 += p[4];
          z3 += p[6];
        }
      }
      float si = sigmoidf_(z0);
      float sf = sigmoidf_(z1);
      float tg = tanhf(z2);
      float so = sigmoidf_(z3);
      creg = fmaf(sf, creg, si * tg);
      float h = so * tanhf(creg);

      float* hp = hbufT + (size_t)((s & 1) ^ 1) * 32768 + (size_t)j * 64 + bu;
      asm volatile("global_store_dword %0, %1, off sc0 sc1"
                   :: "v"(hp), "v"(h) : "memory");

      if (hsB16) hsB16[((size_t)bu * 512 + tt) * 1024 + j] = f2bf(h);
      else       hsF [((size_t)bu * 512 + tt) * 1024 + j] = h;
      if (s == 511 && stateh != nullptr) {
        stateh[bu * 1024 + j] = h;
        statec[bu * 1024 + j] = creg;
      }
    }

    if (s < 511) {
      asm volatile("s_waitcnt vmcnt(0)" ::: "memory");
      __syncthreads();
      if (tid == 0) {
        unsigned a = __hip_atomic_fetch_add(leaf, 1u, __ATOMIC_RELAXED,
                                            __HIP_MEMORY_SCOPE_AGENT) + 1u;
        if (a == 32u * (unsigned)(s + 1)) {
          unsigned r = __hip_atomic_fetch_add(root, 1u, __ATOMIC_RELAXED,
                                              __HIP_MEMORY_SCOPE_AGENT) + 1u;
          if (r == 8u * (unsigned)(s + 1))
            __hip_atomic_fetch_add(gen, 1u, __ATOMIC_RELAXED,
                                   __HIP_MEMORY_SCOPE_AGENT);
        }
      }
      if (tid < 128) {
        const int tn = reverse ? (511 - (s + 1)) : (s + 1);
        const unsigned short* p = xzb + (size_t)tn * 2048;
        zx0 = bf2f(p[0]); zx1 = bf2f(p[512]);
        zx2 = bf2f(p[1024]); zx3 = bf2f(p[1536]);
      }
      if (tid == 0) {
        while (__hip_atomic_load(gen, __ATOMIC_RELAXED,
                                 __HIP_MEMORY_SCOPE_AGENT) <= (unsigned)s)
          __builtin_amdgcn_s_sleep(1);
      }
      __syncthreads();
    }
  }
}

// ---------------------------------------------------------------------------
extern "C" void kernel_launch(void* const* d_in, const int* in_sizes, int n_in,
                              void* d_out, int out_size, void* d_ws, size_t ws_size,
                              hipStream_t stream) {
  const int*   ids = (const int*)d_in[0];
  const float* emb = (const float*)d_in[1];
  const float* W1f = (const float*)d_in[2];
  const float* U1f = (const float*)d_in[3];
  const float* b1f = (const float*)d_in[4];
  const float* W1b = (const float*)d_in[5];
  const float* U1b = (const float*)d_in[6];
  const float* b1b = (const float*)d_in[7];
  const float* W2f = (const float*)d_in[8];
  const float* U2f = (const float*)d_in[9];
  const float* b2f = (const float*)d_in[10];
  const float* W2b = (const float*)d_in[11];
  const float* U2b = (const float*)d_in[12];
  const float* b2b = (const float*)d_in[13];
  float* out = (float*)d_out;

  char* ws = (char*)d_ws;
  const size_t BIG_NEED = 285741056ull;   // 272.5 MB

  if (ws_size >= BIG_NEED) {
    // ---- BIG layout: xzF | xzB | Ut x4 | hbuf | bar ; l1 stashed in d_out ----
    unsigned short* xzF = (unsigned short*)(ws + 0ull);
    unsigned short* xzB = (unsigned short*)(ws + 134217728ull);
    float* Ut1f = (float*)(ws + 268435456ull);
    float* Ut1b = Ut1f + 1048576;
    float* Ut2f = Ut1b + 1048576;
    float* Ut2b = Ut2f + 1048576;
    float* hbuf = (float*)(ws + 285212672ull);
    unsigned* bar = (unsigned*)(ws + 285736960ull);
    unsigned short* l1d = (unsigned short*)d_out;   // bf16 stash, dead before lstm2

    transpose_u<<<1024, 256, 0, stream>>>(U1f, Ut1f);
    transpose_u<<<1024, 256, 0, stream>>>(U1b, Ut1b);
    transpose_u<<<1024, 256, 0, stream>>>(U2f, Ut2f);
    transpose_u<<<1024, 256, 0, stream>>>(U2b, Ut2b);

    // layer-1 projections
    gemm_bias<false><<<8192, 256, 0, stream>>>(emb, W1f, b1f, xzF, 512, ids);
    gemm_bias<false><<<8192, 256, 0, stream>>>(emb, W1b, b1b, xzB, 512, ids);
    hipMemsetAsync(bar, 0, 4096, stream);
    lstm_fused<<<NBLK_LSTM, 256, 0, stream>>>(xzF, xzB, Ut1f, Ut1b,
                                              nullptr, l1d, hbuf,
                                              nullptr, nullptr, bar);
    // layer-2 projections (read bf16 l1 from d_out)
    gemm_bias<true><<<8192, 256, 0, stream>>>(l1d, W2f, b2f, xzF, 1024, nullptr);
    gemm_bias<true><<<8192, 256, 0, stream>>>(l1d, W2b, b2b, xzB, 1024, nullptr);
    hipMemsetAsync(bar, 0, 4096, stream);
    lstm_fused<<<NBLK_LSTM, 256, 0, stream>>>(xzF, xzB, Ut2f, Ut2b,
                                              out, nullptr, hbuf,
                                              out + 33554432, out + 33619968, bar);
  } else {
    // ---- round-4 fallback (208.6 MB) ----
    unsigned short* xz  = (unsigned short*)(ws + 0ull);
    unsigned short* l1  = (unsigned short*)(ws + 134217728ull);
    float* Ut1f = (float*)(ws + 201326592ull);
    float* Ut1b = Ut1f + 1048576;
    float* Ut2f = Ut1b + 1048576;
    float* Ut2b = Ut2f + 1048576;
    float* hbufT = (float*)(ws + 218103808ull);
    unsigned* bar  = (unsigned*)(ws + 218365952ull);

    transpose_u<<<1024, 256, 0, stream>>>(U1f, Ut1f);
    transpose_u<<<1024, 256, 0, stream>>>(U1b, Ut1b);
    transpose_u<<<1024, 256, 0, stream>>>(U2f, Ut2f);
    transpose_u<<<1024, 256, 0, stream>>>(U2b, Ut2b);

    gemm_bias<false><<<8192, 256, 0, stream>>>(emb, W1f, b1f, xz, 512, ids);
    hipMemsetAsync(bar, 0, 4096, stream);
    lstm_dir_k<<<NBLK_LSTM, 256, 0, stream>>>(xz, Ut1f, nullptr, l1 + 0, hbufT,
                                              nullptr, nullptr, 0, bar);
    gemm_bias<false><<<8192, 256, 0, stream>>>(emb, W1b, b1b, xz, 512, ids);
    hipMemsetAsync(bar, 0, 4096, stream);
    lstm_dir_k<<<NBLK_LSTM, 256, 0, stream>>>(xz, Ut1b, nullptr, l1 + 512, hbufT,
                                              nullptr, nullptr, 1, bar);
    gemm_bias<true><<<8192, 256, 0, stream>>>(l1, W2f, b2f, xz, 1024, nullptr);
    hipMemsetAsync(bar, 0, 4096, stream);
    lstm_dir_k<<<NBLK_LSTM, 256, 0, stream>>>(xz, Ut2f, out, nullptr, hbufT,
                                              out + 33554432, out + 33619968, 0, bar);
    gemm_bias<true><<<8192, 256, 0, stream>>>(l1, W2b, b2b, xz, 1024, nullptr);
    hipMemsetAsync(bar, 0, 4096, stream);
    lstm_dir_k<<<NBLK_LSTM, 256, 0, stream>>>(xz, Ut2b, out + 512, nullptr, hbufT,
                                              out + 33554432 + 512, out + 33619968 + 512, 1, bar);
  }
}

// Round 6
// 14677.232 us; speedup vs baseline: 9.5834x; 1.0969x over previous
//
#include <hip/hip_runtime.h>
#include <math.h>

// ---------------------------------------------------------------------------
// Encoder: 2-layer bidirectional LSTM, B=64, T=512, E=H=512, fp32 in/out.
// Round 6: recurrence repartitioned (64 jg x 2 bg per dir) -> h staged once
// per block into LDS (IF h-traffic 64 MB -> 16 MB per epoch). XOR-swizzled
// granules for conflict-free LDS; producers store h pre-swizzled; flat 8-leaf
// barrier with direct polling.
// ---------------------------------------------------------------------------

#define NBLK_LSTM 256

__device__ __forceinline__ float bf2f(unsigned short u) {
  return __uint_as_float(((unsigned)u) << 16);
}
__device__ __forceinline__ unsigned short f2bf(float f) {
  unsigned u = __float_as_uint(f);
  unsigned r = (u + 0x7FFFu + ((u >> 16) & 1u)) >> 16;
  return (unsigned short)r;
}
__device__ __forceinline__ float sigmoidf_(float x) {
  return 1.0f / (1.0f + expf(-x));
}

// ---------------- U transpose: Ut[col][k] = U[k][col] (fp32) ----------------
__global__ __launch_bounds__(256) void transpose_u(const float* __restrict__ U,
                                                   float* __restrict__ Ut) {
  __shared__ float tile[32][33];
  int kt = blockIdx.x & 15;
  int ct = blockIdx.x >> 4;
  int k0 = kt * 32, c0 = ct * 32;
  int tx = threadIdx.x & 31, ty = threadIdx.x >> 5;
#pragma unroll
  for (int i = 0; i < 32; i += 8)
    tile[ty + i][tx] = U[(size_t)(k0 + ty + i) * 2048 + c0 + tx];
  __syncthreads();
#pragma unroll
  for (int i = 0; i < 32; i += 8)
    Ut[(size_t)(c0 + ty + i) * 512 + k0 + tx] = tile[tx][ty + i];
}

// ---------------- GEMM: C_bf16[M,2048] = A[M,K] @ W[K,2048] + bias ----------
template <bool ABF16>
__global__ __launch_bounds__(256) void gemm_bias(const void* __restrict__ Av,
                                                 const float* __restrict__ W,
                                                 const float* __restrict__ bias,
                                                 unsigned short* __restrict__ C,
                                                 int K,
                                                 const int* __restrict__ gather) {
  __shared__ float As[16][132];
  __shared__ float Bs[16][68];
  const int bm = blockIdx.x & 255;
  const int bn = blockIdx.x >> 8;
  const int m0 = bm * 128, n0 = bn * 64;
  const int tid = threadIdx.x;
  const int tx = tid & 15, ty = tid >> 4;

  float acc[8][4];
#pragma unroll
  for (int r = 0; r < 8; r++)
#pragma unroll
    for (int q = 0; q < 4; q++) acc[r][q] = 0.0f;

  for (int k0 = 0; k0 < K; k0 += 16) {
#pragma unroll
    for (int s = 0; s < 2; s++) {
      int slot = tid + s * 256;
      int row = slot >> 2;
      int f4 = (slot & 3) * 4;
      if (ABF16) {
        const unsigned short* A = (const unsigned short*)Av;
        size_t abase = (size_t)(m0 + row) * K;
        ushort4 v = *(const ushort4*)&A[abase + k0 + f4];
        As[f4 + 0][row] = bf2f(v.x);
        As[f4 + 1][row] = bf2f(v.y);
        As[f4 + 2][row] = bf2f(v.z);
        As[f4 + 3][row] = bf2f(v.w);
      } else {
        const float* A = (const float*)Av;
        size_t abase = gather ? ((size_t)gather[m0 + row] * 512)
                              : ((size_t)(m0 + row) * K);
        float4 v = *(const float4*)&A[abase + k0 + f4];
        As[f4 + 0][row] = v.x;
        As[f4 + 1][row] = v.y;
        As[f4 + 2][row] = v.z;
        As[f4 + 3][row] = v.w;
      }
    }
    {
      int kr = tid >> 4;
      int nf = (tid & 15) * 4;
      *(float4*)&Bs[kr][nf] = *(const float4*)&W[(size_t)(k0 + kr) * 2048 + n0 + nf];
    }
    __syncthreads();
#pragma unroll
    for (int k = 0; k < 16; k++) {
      float4 a0 = *(const float4*)&As[k][ty * 8];
      float4 a1 = *(const float4*)&As[k][ty * 8 + 4];
      float4 b0 = *(const float4*)&Bs[k][tx * 4];
      float av[8] = {a0.x, a0.y, a0.z, a0.w, a1.x, a1.y, a1.z, a1.w};
      float bv[4] = {b0.x, b0.y, b0.z, b0.w};
#pragma unroll
      for (int r = 0; r < 8; r++)
#pragma unroll
        for (int q = 0; q < 4; q++)
          acc[r][q] = fmaf(av[r], bv[q], acc[r][q]);
    }
    __syncthreads();
  }

  float4 bb = *(const float4*)&bias[n0 + tx * 4];
#pragma unroll
  for (int r = 0; r < 8; r++) {
    ushort4 o;
    o.x = f2bf(acc[r][0] + bb.x);
    o.y = f2bf(acc[r][1] + bb.y);
    o.z = f2bf(acc[r][2] + bb.z);
    o.w = f2bf(acc[r][3] + bb.w);
    *(ushort4*)&C[(size_t)(m0 + ty * 8 + r) * 2048 + n0 + tx * 4] = o;
  }
}

// ============================================================================
// Fused bidirectional recurrence, 2-D partition.
// 256 blocks: dir = bid>>7; per dir 128 blocks = 64 jg (8 j) x 2 bg (32 b).
// LDS: U slice [512k][32c] 64 KB + h slice [512k][32b] 64 KB + p_lds 16.5 KB.
// Granule XOR swizzle: 4-float granule g of row k lives at slot g ^ ((k>>5)&3)
// -> all compute-phase LDS reads are <=2-way (free). Producers store h into
// hbuf pre-swizzled; consumers stage LINEAR (rule: swizzle source + read).
// hbuf: [dir][buf][bg][512 k][32 b'] fp32 (swizzled within rows).
// ============================================================================
__global__ __launch_bounds__(256, 1) void lstm_fused(
    const unsigned short* __restrict__ xzF,
    const unsigned short* __restrict__ xzB,
    const float* __restrict__ UtF,
    const float* __restrict__ UtB,
    float* __restrict__ outF32,          // fp32 out stride 1024 (or null)
    unsigned short* __restrict__ outB16, // bf16 out stride 1024 (or null)
    float* __restrict__ hbuf,
    float* __restrict__ stateh, float* __restrict__ statec,
    unsigned* __restrict__ bar) {
  __shared__ float u_lds[512 * 32];     // 64 KB
  __shared__ float h_lds[512 * 32];     // 64 KB
  __shared__ float p_lds[4][32][33];    // 16.5 KB

  const int tid = threadIdx.x;
  const int bid = blockIdx.x;
  const int dir = bid >> 7;
  const int jg  = (bid & 127) >> 1;     // 0..63
  const int bg  = bid & 1;              // 0..1

  const unsigned short* xz = dir ? xzB : xzF;
  const float* Ut = dir ? UtB : UtF;

  // ---- stage U slice (once): col c = g*8+jl -> Ut col g*512 + jg*8 + jl ----
  {
    int c  = tid >> 3;                  // 0..31
    int g  = c >> 3, jlc = c & 7;
    int k0 = (tid & 7) * 64;
    const float* src = Ut + ((size_t)(g * 512 + jg * 8 + jlc)) * 512 + k0;
    for (int kk = 0; kk < 64; kk++) {
      int k = k0 + kk;
      int slot = (((c >> 2) ^ ((k >> 5) & 3)) << 2) | (c & 3);
      u_lds[k * 32 + slot] = src[kk];
    }
  }

  // compute-phase identity: tid = ks*16 + bq*4 + cq
  const int cq  = tid & 3;
  const int bq  = (tid >> 2) & 3;
  const int ks  = tid >> 4;             // 0..15 (32 k each)
  const int ks3 = ks & 3;
  const int wv  = tid >> 6;             // wave
  const int lane = tid & 63;

  // update-phase identity: tid = ub*8 + jl
  const int ub = tid >> 3;              // 0..31
  const int jl = tid & 7;
  const int b  = bg * 32 + ub;
  const int j  = jg * 8 + jl;

  const unsigned short* xzb = xz + (size_t)b * (512 * 2048) + j;
  const size_t slice_bg = (size_t)dir * 65536 + (size_t)bg * 16384;
  const int hswz = ((((ub >> 2) ^ ((j >> 5) & 3)) << 2) | (ub & 3));

  float creg = 0.0f;
  float zx0, zx1, zx2, zx3;
  {
    const unsigned short* p = xzb + (size_t)(dir ? 511 : 0) * 2048;
    zx0 = bf2f(p[0]); zx1 = bf2f(p[512]);
    zx2 = bf2f(p[1024]); zx3 = bf2f(p[1536]);
  }

  for (int s = 0; s < 512; s++) {
    const int tt = dir ? (511 - s) : s;

    if (s > 0) {
      // ---- stage own wave's h k-range (128 k x 32 b = 16 KB) ----
      const float* src = hbuf + slice_bg + (size_t)(s & 1) * 32768 +
                         wv * 4096 + lane * 4;
      float4 hv[16];
#pragma unroll
      for (int i = 0; i < 16; i++) {
        const float* p = src + i * 256;
        asm volatile("global_load_dwordx4 %0, %1, off sc0 sc1"
                     : "=v"(hv[i]) : "v"(p) : "memory");
      }
      asm volatile("s_waitcnt vmcnt(0)" ::: "memory");
      __builtin_amdgcn_sched_barrier(0);
      float* dst = h_lds + wv * 4096 + lane * 4;
#pragma unroll
      for (int i = 0; i < 16; i++) *(float4*)(dst + i * 256) = hv[i];

      // ---- compute: 8b x 8c x 32k register tile ----
      float acc[8][8];
#pragma unroll
      for (int bi = 0; bi < 8; bi++)
#pragma unroll
        for (int ci = 0; ci < 8; ci++) acc[bi][ci] = 0.0f;

      const int sA = ((bq * 2) ^ ks3) << 2, sB = ((bq * 2 + 1) ^ ks3) << 2;
      const int sC = ((cq * 2) ^ ks3) << 2, sD = ((cq * 2 + 1) ^ ks3) << 2;
#pragma unroll 4
      for (int kk = 0; kk < 32; kk++) {
        const int k = ks * 32 + kk;
        const float* hrow = h_lds + k * 32;
        const float* urow = u_lds + k * 32;
        float4 ha = *(const float4*)(hrow + sA);
        float4 hb = *(const float4*)(hrow + sB);
        float4 ua = *(const float4*)(urow + sC);
        float4 ub4 = *(const float4*)(urow + sD);
        float hvv[8] = {ha.x, ha.y, ha.z, ha.w, hb.x, hb.y, hb.z, hb.w};
        float uvv[8] = {ua.x, ua.y, ua.z, ua.w, ub4.x, ub4.y, ub4.z, ub4.w};
#pragma unroll
        for (int bi = 0; bi < 8; bi++)
#pragma unroll
          for (int ci = 0; ci < 8; ci++)
            acc[bi][ci] = fmaf(hvv[bi], uvv[ci], acc[bi][ci]);
      }
      // in-wave reduce over ks&3 (lane bits 4,5), then p_lds
#pragma unroll
      for (int bi = 0; bi < 8; bi++)
#pragma unroll
        for (int ci = 0; ci < 8; ci++) {
          float v = acc[bi][ci];
          v += __shfl_xor(v, 16);
          v += __shfl_xor(v, 32);
          acc[bi][ci] = v;
        }
      if ((tid & 48) == 0) {
#pragma unroll
        for (int bi = 0; bi < 8; bi++) {
          float4 pa = {acc[bi][0], acc[bi][1], acc[bi][2], acc[bi][3]};
          float4 pb = {acc[bi][4], acc[bi][5], acc[bi][6], acc[bi][7]};
          *(float4*)&p_lds[wv][bq * 8 + bi][cq * 8] = pa;
          *(float4*)&p_lds[wv][bq * 8 + bi][cq * 8 + 4] = pb;
        }
      }
    }
    __syncthreads();

    // ---- update: all 256 threads, thread owns (b, j) ----
    float h;
    {
      float z0 = zx0, z1 = zx1, z2 = zx2, z3 = zx3;
      if (s > 0) {
#pragma unroll
        for (int w = 0; w < 4; w++) {
          z0 += p_lds[w][ub][jl];
          z1 += p_lds[w][ub][8 + jl];
          z2 += p_lds[w][ub][16 + jl];
          z3 += p_lds[w][ub][24 + jl];
        }
      }
      float si = sigmoidf_(z0);
      float sf = sigmoidf_(z1);
      float tg = tanhf(z2);
      float so = sigmoidf_(z3);
      creg = fmaf(sf, creg, si * tg);
      h = so * tanhf(creg);
    }

    if (s < 511) {
      // h store (pre-swizzled, IF-coherent)
      float* hp = hbuf + slice_bg + (size_t)((s & 1) ^ 1) * 32768 +
                  (size_t)j * 32 + hswz;
      asm volatile("global_store_dword %0, %1, off sc0 sc1"
                   :: "v"(hp), "v"(h) : "memory");
      asm volatile("s_waitcnt vmcnt(0)" ::: "memory");
      __syncthreads();
      if (tid == 0)
        __hip_atomic_fetch_add(bar + ((bid & 7) << 5), 1u, __ATOMIC_RELAXED,
                               __HIP_MEMORY_SCOPE_AGENT);
      // ---- barrier shadow: output store + next-xz prefetch ----
      const int col = dir * 512 + j;
      if (outB16) outB16[((size_t)b * 512 + tt) * 1024 + col] = f2bf(h);
      else        outF32[((size_t)b * 512 + tt) * 1024 + col] = h;
      {
        const int tn = dir ? (510 - s) : (s + 1);
        const unsigned short* p = xzb + (size_t)tn * 2048;
        zx0 = bf2f(p[0]); zx1 = bf2f(p[512]);
        zx2 = bf2f(p[1024]); zx3 = bf2f(p[1536]);
      }
      if (tid < 8) {
        const unsigned tgt = 32u * (unsigned)(s + 1);
        while (__hip_atomic_load(bar + (tid << 5), __ATOMIC_RELAXED,
                                 __HIP_MEMORY_SCOPE_AGENT) < tgt)
          __builtin_amdgcn_s_sleep(1);
      }
      __syncthreads();
    } else {
      const int col = dir * 512 + j;
      if (outB16) outB16[((size_t)b * 512 + tt) * 1024 + col] = f2bf(h);
      else        outF32[((size_t)b * 512 + tt) * 1024 + col] = h;
      if (stateh != nullptr) {
        stateh[b * 1024 + col] = h;
        statec[b * 1024 + col] = creg;
      }
    }
  }
}

// ---------------------------------------------------------------------------
extern "C" void kernel_launch(void* const* d_in, const int* in_sizes, int n_in,
                              void* d_out, int out_size, void* d_ws, size_t ws_size,
                              hipStream_t stream) {
  const int*   ids = (const int*)d_in[0];
  const float* emb = (const float*)d_in[1];
  const float* W1f = (const float*)d_in[2];
  const float* U1f = (const float*)d_in[3];
  const float* b1f = (const float*)d_in[4];
  const float* W1b = (const float*)d_in[5];
  const float* U1b = (const float*)d_in[6];
  const float* b1b = (const float*)d_in[7];
  const float* W2f = (const float*)d_in[8];
  const float* U2f = (const float*)d_in[9];
  const float* b2f = (const float*)d_in[10];
  const float* W2b = (const float*)d_in[11];
  const float* U2b = (const float*)d_in[12];
  const float* b2b = (const float*)d_in[13];
  float* out = (float*)d_out;

  char* ws = (char*)d_ws;
  // BIG layout (proved available in round 5): ~272.5 MB
  //   xzF bf16 [32768][2048] @ 0            (134,217,728)
  //   xzB bf16 [32768][2048] @ 134,217,728  (134,217,728)
  //   Ut  fp32 4x[2048][512] @ 268,435,456  ( 16,777,216)
  //   hbuf fp32 [2][2][2][512][32] @ 285,212,672 (524,288)
  //   bar @ 285,736,960
  unsigned short* xzF = (unsigned short*)(ws + 0ull);
  unsigned short* xzB = (unsigned short*)(ws + 134217728ull);
  float* Ut1f = (float*)(ws + 268435456ull);
  float* Ut1b = Ut1f + 1048576;
  float* Ut2f = Ut1b + 1048576;
  float* Ut2b = Ut2f + 1048576;
  float* hbuf = (float*)(ws + 285212672ull);
  unsigned* bar = (unsigned*)(ws + 285736960ull);
  unsigned short* l1d = (unsigned short*)d_out;   // bf16 stash, dead before lstm2

  transpose_u<<<1024, 256, 0, stream>>>(U1f, Ut1f);
  transpose_u<<<1024, 256, 0, stream>>>(U1b, Ut1b);
  transpose_u<<<1024, 256, 0, stream>>>(U2f, Ut2f);
  transpose_u<<<1024, 256, 0, stream>>>(U2b, Ut2b);

  // layer-1 projections
  gemm_bias<false><<<8192, 256, 0, stream>>>(emb, W1f, b1f, xzF, 512, ids);
  gemm_bias<false><<<8192, 256, 0, stream>>>(emb, W1b, b1b, xzB, 512, ids);
  hipMemsetAsync(bar, 0, 4096, stream);
  lstm_fused<<<NBLK_LSTM, 256, 0, stream>>>(xzF, xzB, Ut1f, Ut1b,
                                            nullptr, l1d, hbuf,
                                            nullptr, nullptr, bar);
  // layer-2 projections (read bf16 l1 from d_out)
  gemm_bias<true><<<8192, 256, 0, stream>>>(l1d, W2f, b2f, xzF, 1024, nullptr);
  gemm_bias<true><<<8192, 256, 0, stream>>>(l1d, W2b, b2b, xzB, 1024, nullptr);
  hipMemsetAsync(bar, 0, 4096, stream);
  lstm_fused<<<NBLK_LSTM, 256, 0, stream>>>(xzF, xzB, Ut2f, Ut2b,
                                            out, nullptr, hbuf,
                                            out + 33554432, out + 33619968, bar);
}

// Round 8
// 8843.086 us; speedup vs baseline: 15.9060x; 1.6597x over previous
//
#include <hip/hip_runtime.h>
#include <math.h>

// ---------------------------------------------------------------------------
// Encoder: 2-layer bidirectional LSTM, B=64, T=512, E=H=512, fp32 in/out.
// Round 8 (= round 7 resubmitted after infra failure):
// recurrence h@U moved to MFMA (32x32x16 bf16, 3-term hi/lo split for
// fp32-grade accuracy). U fragments in registers (loop-invariant),
// h in XOR-swizzled bf16 LDS planes, producers store h pre-swizzled.
// Barrier split into 4 independent 64-block groups (dir x bg).
// ---------------------------------------------------------------------------

#define NBLK_LSTM 256

typedef __attribute__((ext_vector_type(8))) short bf16x8;
typedef __attribute__((ext_vector_type(16))) float f32x16;

__device__ __forceinline__ float bf2f(unsigned short u) {
  return __uint_as_float(((unsigned)u) << 16);
}
__device__ __forceinline__ unsigned short f2bf(float f) {
  unsigned u = __float_as_uint(f);
  unsigned r = (u + 0x7FFFu + ((u >> 16) & 1u)) >> 16;
  return (unsigned short)r;
}
__device__ __forceinline__ float fsigmoid(float x) {
  return 1.0f / (1.0f + __expf(-x));
}
__device__ __forceinline__ float ftanh(float x) {
  return 1.0f - 2.0f / (1.0f + __expf(2.0f * x));
}

// ---------------- U transpose: Ut[col][k] = U[k][col] (fp32) ----------------
__global__ __launch_bounds__(256) void transpose_u(const float* __restrict__ U,
                                                   float* __restrict__ Ut) {
  __shared__ float tile[32][33];
  int kt = blockIdx.x & 15;
  int ct = blockIdx.x >> 4;
  int k0 = kt * 32, c0 = ct * 32;
  int tx = threadIdx.x & 31, ty = threadIdx.x >> 5;
#pragma unroll
  for (int i = 0; i < 32; i += 8)
    tile[ty + i][tx] = U[(size_t)(k0 + ty + i) * 2048 + c0 + tx];
  __syncthreads();
#pragma unroll
  for (int i = 0; i < 32; i += 8)
    Ut[(size_t)(c0 + ty + i) * 512 + k0 + tx] = tile[tx][ty + i];
}

// ---------------- GEMM: C_bf16[M,2048] = A[M,K] @ W[K,2048] + bias ----------
template <bool ABF16>
__global__ __launch_bounds__(256) void gemm_bias(const void* __restrict__ Av,
                                                 const float* __restrict__ W,
                                                 const float* __restrict__ bias,
                                                 unsigned short* __restrict__ C,
                                                 int K,
                                                 const int* __restrict__ gather) {
  __shared__ float As[16][132];
  __shared__ float Bs[16][68];
  const int bm = blockIdx.x & 255;
  const int bn = blockIdx.x >> 8;
  const int m0 = bm * 128, n0 = bn * 64;
  const int tid = threadIdx.x;
  const int tx = tid & 15, ty = tid >> 4;

  float acc[8][4];
#pragma unroll
  for (int r = 0; r < 8; r++)
#pragma unroll
    for (int q = 0; q < 4; q++) acc[r][q] = 0.0f;

  for (int k0 = 0; k0 < K; k0 += 16) {
#pragma unroll
    for (int s = 0; s < 2; s++) {
      int slot = tid + s * 256;
      int row = slot >> 2;
      int f4 = (slot & 3) * 4;
      if (ABF16) {
        const unsigned short* A = (const unsigned short*)Av;
        size_t abase = (size_t)(m0 + row) * K;
        ushort4 v = *(const ushort4*)&A[abase + k0 + f4];
        As[f4 + 0][row] = bf2f(v.x);
        As[f4 + 1][row] = bf2f(v.y);
        As[f4 + 2][row] = bf2f(v.z);
        As[f4 + 3][row] = bf2f(v.w);
      } else {
        const float* A = (const float*)Av;
        size_t abase = gather ? ((size_t)gather[m0 + row] * 512)
                              : ((size_t)(m0 + row) * K);
        float4 v = *(const float4*)&A[abase + k0 + f4];
        As[f4 + 0][row] = v.x;
        As[f4 + 1][row] = v.y;
        As[f4 + 2][row] = v.z;
        As[f4 + 3][row] = v.w;
      }
    }
    {
      int kr = tid >> 4;
      int nf = (tid & 15) * 4;
      *(float4*)&Bs[kr][nf] = *(const float4*)&W[(size_t)(k0 + kr) * 2048 + n0 + nf];
    }
    __syncthreads();
#pragma unroll
    for (int k = 0; k < 16; k++) {
      float4 a0 = *(const float4*)&As[k][ty * 8];
      float4 a1 = *(const float4*)&As[k][ty * 8 + 4];
      float4 b0 = *(const float4*)&Bs[k][tx * 4];
      float av[8] = {a0.x, a0.y, a0.z, a0.w, a1.x, a1.y, a1.z, a1.w};
      float bv[4] = {b0.x, b0.y, b0.z, b0.w};
#pragma unroll
      for (int r = 0; r < 8; r++)
#pragma unroll
        for (int q = 0; q < 4; q++)
          acc[r][q] = fmaf(av[r], bv[q], acc[r][q]);
    }
    __syncthreads();
  }

  float4 bb = *(const float4*)&bias[n0 + tx * 4];
#pragma unroll
  for (int r = 0; r < 8; r++) {
    ushort4 o;
    o.x = f2bf(acc[r][0] + bb.x);
    o.y = f2bf(acc[r][1] + bb.y);
    o.z = f2bf(acc[r][2] + bb.z);
    o.w = f2bf(acc[r][3] + bb.w);
    *(ushort4*)&C[(size_t)(m0 + ty * 8 + r) * 2048 + n0 + tx * 4] = o;
  }
}

// ============================================================================
// Fused bidirectional recurrence, MFMA edition.
// 256 blocks: dir = bid>>7, jg = (bid&127)>>1 (8 j-cols), bg = bid&1 (32 b).
// Per block per step: z[32 b][32 c] = h[32 b][512 k] @ U[512 k][32 c] via
// v_mfma_f32_32x32x16_bf16, K split 4 ways across waves (reduce in update).
// 3-term split: hh*Uh + hl*Uh + hh*Ul (fp32-grade). U frags in VGPR.
// h planes in LDS (bf16 hh/hl, XOR swizzle byte^=(b&7)<<4), staged from IF;
// producers store pre-swizzled 2B sc0sc1. 4 independent barrier groups.
// hbuf slices: [grp=dir*2+bg][buf][plane hh/hl][32 b][512 j'] bf16, 64KB each.
// ============================================================================
__global__ __launch_bounds__(256, 1) void lstm_fused(
    const unsigned short* __restrict__ xzF,
    const unsigned short* __restrict__ xzB,
    const float* __restrict__ UtF,
    const float* __restrict__ UtB,
    float* __restrict__ outF32,          // fp32 out stride 1024 (or null)
    unsigned short* __restrict__ outB16, // bf16 out stride 1024 (or null)
    float* __restrict__ hbuf,
    float* __restrict__ stateh, float* __restrict__ statec,
    unsigned* __restrict__ bar) {
  __shared__ __align__(16) char h_lds[65536];     // 2 planes x [32 b][512 k] bf16 (swizzled)
  __shared__ float p_lds[4][32][36];              // per-wave partial z

  const int tid = threadIdx.x;
  const int bid = blockIdx.x;
  const int dir = bid >> 7;
  const int jg  = (bid & 127) >> 1;
  const int bg  = bid & 1;
  const int grp = dir * 2 + bg;

  const unsigned short* xz = dir ? xzB : xzF;
  const float* Ut = dir ? UtB : UtF;
  char* hbuf_c = (char*)hbuf;

  const int l  = tid & 63;
  const int wv = tid >> 6;

  // ---- load U fragments into registers (loop-invariant B operands) ----
  // wave wv owns k in [wv*128, wv*128+128): 8 MFMA slices of K=16.
  // B frag (32x32x16): col = l&31, k = slice*16 + (l>>5)*8 + e.
  bf16x8 uh8[8], ul8[8];
  {
    const int c = l & 31;
    const size_t gcol = (size_t)((c >> 3) * 512 + jg * 8 + (c & 7));
#pragma unroll
    for (int ks = 0; ks < 8; ks++) {
      const float* src = Ut + gcol * 512 + (wv * 8 + ks) * 16 + ((l >> 5) << 3);
      bf16x8 hh, ll;
#pragma unroll
      for (int e = 0; e < 8; e++) {
        float f = src[e];
        unsigned short us = f2bf(f);
        hh[e] = (short)us;
        ll[e] = (short)f2bf(f - bf2f(us));
      }
      uh8[ks] = hh;
      ul8[ks] = ll;
    }
  }

  // update-phase identity: thread = (ub, jl); b = bg*32+ub, j = jg*8+jl
  const int ub = tid >> 3;
  const int jl = tid & 7;
  const int b  = bg * 32 + ub;
  const int j  = jg * 8 + jl;

  unsigned* leafArr = bar + grp * 128;
  unsigned* myleaf  = leafArr + (jg & 7) * 16;

  const unsigned short* xzb = xz + (size_t)b * (512 * 2048) + j;

  float creg = 0.0f;
  float zx0, zx1, zx2, zx3;
  {
    const unsigned short* p = xzb + (size_t)(dir ? 511 : 0) * 2048;
    zx0 = bf2f(p[0]); zx1 = bf2f(p[512]);
    zx2 = bf2f(p[1024]); zx3 = bf2f(p[1536]);
  }

  // A-frag addressing constants: row b' = l&31, XOR swizzle (b'&7)<<4
  const char* hrow = h_lds + (l & 31) * 1024;
  const int axr = (l & 7) << 4;
  const int koff = (l >> 5) << 4;   // (l>>5)*8 bf16 = 16 bytes
  const int hswz_w = (ub & 7) << 4; // producer-side swizzle

  for (int s = 0; s < 512; s++) {
    const int tt = dir ? (511 - s) : s;

    if (s > 0) {
      // ---- stage h slice (64 KB) from IF, linear (swizzle pre-applied) ----
      const char* sb = hbuf_c + (size_t)(grp * 2 + (s & 1)) * 65536;
      float4 hv[16];
#pragma unroll
      for (int i = 0; i < 16; i++) {
        const float* p = (const float*)(sb + (size_t)(i * 256 + tid) * 16);
        asm volatile("global_load_dwordx4 %0, %1, off sc0 sc1"
                     : "=v"(hv[i]) : "v"(p) : "memory");
      }
      asm volatile("s_waitcnt vmcnt(0)" ::: "memory");
      __builtin_amdgcn_sched_barrier(0);
#pragma unroll
      for (int i = 0; i < 16; i++)
        *(float4*)(h_lds + (size_t)(i * 256 + tid) * 16) = hv[i];
    }
    __syncthreads();

    if (s > 0) {
      // ---- MFMA: wave wv accumulates its K-quarter of z[32][32] ----
      f32x16 acc;
#pragma unroll
      for (int r = 0; r < 16; r++) acc[r] = 0.0f;
#pragma unroll
      for (int ks = 0; ks < 8; ks++) {
        const int boff = (((wv * 8 + ks) << 5) + koff) ^ axr;
        bf16x8 ahh = *(const bf16x8*)(hrow + boff);
        bf16x8 ahl = *(const bf16x8*)(hrow + 32768 + boff);
        acc = __builtin_amdgcn_mfma_f32_32x32x16_bf16(ahh, uh8[ks], acc, 0, 0, 0);
        acc = __builtin_amdgcn_mfma_f32_32x32x16_bf16(ahl, uh8[ks], acc, 0, 0, 0);
        acc = __builtin_amdgcn_mfma_f32_32x32x16_bf16(ahh, ul8[ks], acc, 0, 0, 0);
      }
      // C layout (verified): col = l&31, row = (r&3) + 8*(r>>2) + 4*(l>>5)
#pragma unroll
      for (int r = 0; r < 16; r++) {
        const int row = (r & 3) + 8 * (r >> 2) + 4 * (l >> 5);
        p_lds[wv][row][l & 31] = acc[r];
      }
    }
    __syncthreads();

    // ---- update: thread owns (b, j); 4-way K-reduce folded in ----
    float h;
    {
      float z0 = zx0, z1 = zx1, z2 = zx2, z3 = zx3;
      if (s > 0) {
#pragma unroll
        for (int w = 0; w < 4; w++) {
          z0 += p_lds[w][ub][jl];
          z1 += p_lds[w][ub][8 + jl];
          z2 += p_lds[w][ub][16 + jl];
          z3 += p_lds[w][ub][24 + jl];
        }
      }
      float si = fsigmoid(z0);
      float sf = fsigmoid(z1);
      float tg = ftanh(z2);
      float so = fsigmoid(z3);
      creg = fmaf(sf, creg, si * tg);
      h = so * ftanh(creg);
    }

    const int col = dir * 512 + j;
    if (s < 511) {
      // ---- h store: split bf16 pair, pre-swizzled, IF-coherent ----
      unsigned short hhs = f2bf(h);
      unsigned short hls = f2bf(h - bf2f(hhs));
      char* db = hbuf_c + (size_t)(grp * 2 + ((s & 1) ^ 1)) * 65536;
      char* pj = db + ub * 1024 + ((j * 2) ^ hswz_w);
      unsigned vh = hhs, vl = hls;
      asm volatile("global_store_short %0, %1, off sc0 sc1"
                   :: "v"(pj), "v"(vh) : "memory");
      asm volatile("global_store_short %0, %1, off sc0 sc1"
                   :: "v"(pj + 32768), "v"(vl) : "memory");
      asm volatile("s_waitcnt vmcnt(0)" ::: "memory");
      __syncthreads();
      if (tid == 0)
        __hip_atomic_fetch_add(myleaf, 1u, __ATOMIC_RELAXED,
                               __HIP_MEMORY_SCOPE_AGENT);
      // ---- barrier shadow: output store + next-xz prefetch ----
      if (outB16) outB16[((size_t)b * 512 + tt) * 1024 + col] = f2bf(h);
      else        outF32[((size_t)b * 512 + tt) * 1024 + col] = h;
      {
        const int tn = dir ? (510 - s) : (s + 1);
        const unsigned short* p = xzb + (size_t)tn * 2048;
        zx0 = bf2f(p[0]); zx1 = bf2f(p[512]);
        zx2 = bf2f(p[1024]); zx3 = bf2f(p[1536]);
      }
      if (tid < 8) {
        const unsigned tgt = 8u * (unsigned)(s + 1);
        while (__hip_atomic_load(leafArr + tid * 16, __ATOMIC_RELAXED,
                                 __HIP_MEMORY_SCOPE_AGENT) < tgt)
          __builtin_amdgcn_s_sleep(1);
      }
      __syncthreads();
    } else {
      if (outB16) outB16[((size_t)b * 512 + tt) * 1024 + col] = f2bf(h);
      else        outF32[((size_t)b * 512 + tt) * 1024 + col] = h;
      if (stateh != nullptr) {
        stateh[b * 1024 + col] = h;
        statec[b * 1024 + col] = creg;
      }
    }
  }
}

// ---------------------------------------------------------------------------
extern "C" void kernel_launch(void* const* d_in, const int* in_sizes, int n_in,
                              void* d_out, int out_size, void* d_ws, size_t ws_size,
                              hipStream_t stream) {
  const int*   ids = (const int*)d_in[0];
  const float* emb = (const float*)d_in[1];
  const float* W1f = (const float*)d_in[2];
  const float* U1f = (const float*)d_in[3];
  const float* b1f = (const float*)d_in[4];
  const float* W1b = (const float*)d_in[5];
  const float* U1b = (const float*)d_in[6];
  const float* b1b = (const float*)d_in[7];
  const float* W2f = (const float*)d_in[8];
  const float* U2f = (const float*)d_in[9];
  const float* b2f = (const float*)d_in[10];
  const float* W2b = (const float*)d_in[11];
  const float* U2b = (const float*)d_in[12];
  const float* b2b = (const float*)d_in[13];
  float* out = (float*)d_out;

  char* ws = (char*)d_ws;
  // layout (~272.8 MB):
  //   xzF bf16 [32768][2048] @ 0            (134,217,728)
  //   xzB bf16 [32768][2048] @ 134,217,728  (134,217,728)
  //   Ut  fp32 4x[2048][512] @ 268,435,456  ( 16,777,216)
  //   hbuf 8 slices x 64 KB  @ 285,212,672  (    524,288)
  //   bar                    @ 285,736,960
  unsigned short* xzF = (unsigned short*)(ws + 0ull);
  unsigned short* xzB = (unsigned short*)(ws + 134217728ull);
  float* Ut1f = (float*)(ws + 268435456ull);
  float* Ut1b = Ut1f + 1048576;
  float* Ut2f = Ut1b + 1048576;
  float* Ut2b = Ut2f + 1048576;
  float* hbuf = (float*)(ws + 285212672ull);
  unsigned* bar = (unsigned*)(ws + 285736960ull);
  unsigned short* l1d = (unsigned short*)d_out;   // bf16 stash, dead before lstm2

  transpose_u<<<1024, 256, 0, stream>>>(U1f, Ut1f);
  transpose_u<<<1024, 256, 0, stream>>>(U1b, Ut1b);
  transpose_u<<<1024, 256, 0, stream>>>(U2f, Ut2f);
  transpose_u<<<1024, 256, 0, stream>>>(U2b, Ut2b);

  // layer-1 projections
  gemm_bias<false><<<8192, 256, 0, stream>>>(emb, W1f, b1f, xzF, 512, ids);
  gemm_bias<false><<<8192, 256, 0, stream>>>(emb, W1b, b1b, xzB, 512, ids);
  hipMemsetAsync(bar, 0, 4096, stream);
  lstm_fused<<<NBLK_LSTM, 256, 0, stream>>>(xzF, xzB, Ut1f, Ut1b,
                                            nullptr, l1d, hbuf,
                                            nullptr, nullptr, bar);
  // layer-2 projections (read bf16 l1 from d_out)
  gemm_bias<true><<<8192, 256, 0, stream>>>(l1d, W2f, b2f, xzF, 1024, nullptr);
  gemm_bias<true><<<8192, 256, 0, stream>>>(l1d, W2b, b2b, xzB, 1024, nullptr);
  hipMemsetAsync(bar, 0, 4096, stream);
  lstm_fused<<<NBLK_LSTM, 256, 0, stream>>>(xzF, xzB, Ut2f, Ut2b,
                                            out, nullptr, hbuf,
                                            out + 33554432, out + 33619968, bar);
}

// Round 9
// 7823.116 us; speedup vs baseline: 17.9798x; 1.1304x over previous
//
#include <hip/hip_runtime.h>
#include <math.h>

// ---------------------------------------------------------------------------
// Encoder: 2-layer bidirectional LSTM, B=64, T=512, E=H=512, fp32 in/out.
// Round 9: projection GEMMs moved to MFMA (split-bf16, 2/3-term) — 128x128
// tile, BK=32, reg-prefetch pipeline. W pre-split+transposed into bf16 hi/lo
// planes stashed in d_out's dead region. Recurrence (round-8 MFMA lstm_fused)
// unchanged.
// ---------------------------------------------------------------------------

#define NBLK_LSTM 256

typedef __attribute__((ext_vector_type(8))) short bf16x8;
typedef __attribute__((ext_vector_type(16))) float f32x16;

__device__ __forceinline__ float bf2f(unsigned short u) {
  return __uint_as_float(((unsigned)u) << 16);
}
__device__ __forceinline__ unsigned short f2bf(float f) {
  unsigned u = __float_as_uint(f);
  unsigned r = (u + 0x7FFFu + ((u >> 16) & 1u)) >> 16;
  return (unsigned short)r;
}
__device__ __forceinline__ float fsigmoid(float x) {
  return 1.0f / (1.0f + __expf(-x));
}
__device__ __forceinline__ float ftanh(float x) {
  return 1.0f - 2.0f / (1.0f + __expf(2.0f * x));
}

// ---------------- U transpose: Ut[col][k] = U[k][col] (fp32) ----------------
__global__ __launch_bounds__(256) void transpose_u(const float* __restrict__ U,
                                                   float* __restrict__ Ut) {
  __shared__ float tile[32][33];
  int kt = blockIdx.x & 15;
  int ct = blockIdx.x >> 4;
  int k0 = kt * 32, c0 = ct * 32;
  int tx = threadIdx.x & 31, ty = threadIdx.x >> 5;
#pragma unroll
  for (int i = 0; i < 32; i += 8)
    tile[ty + i][tx] = U[(size_t)(k0 + ty + i) * 2048 + c0 + tx];
  __syncthreads();
#pragma unroll
  for (int i = 0; i < 32; i += 8)
    Ut[(size_t)(c0 + ty + i) * 512 + k0 + tx] = tile[tx][ty + i];
}

// ------------- W transpose + hi/lo split: Wh/Wl[col][K] bf16 ----------------
__global__ __launch_bounds__(256) void transpose_split(
    const float* __restrict__ W, unsigned short* __restrict__ Wh,
    unsigned short* __restrict__ Wl, int K) {
  __shared__ float tile[32][33];
  int tilesK = K >> 5;
  int kt = blockIdx.x % tilesK;
  int ct = blockIdx.x / tilesK;
  int k0 = kt * 32, c0 = ct * 32;
  int tx = threadIdx.x & 31, ty = threadIdx.x >> 5;
#pragma unroll
  for (int i = 0; i < 32; i += 8)
    tile[ty + i][tx] = W[(size_t)(k0 + ty + i) * 2048 + c0 + tx];
  __syncthreads();
#pragma unroll
  for (int i = 0; i < 32; i += 8) {
    float f = tile[tx][ty + i];
    unsigned short h = f2bf(f);
    unsigned short l = f2bf(f - bf2f(h));
    size_t idx = (size_t)(c0 + ty + i) * K + k0 + tx;
    Wh[idx] = h;
    Wl[idx] = l;
  }
}

// ============================================================================
// MFMA GEMM: C_bf16[32768][2048] = A[32768][K] @ W[K][2048] + bias.
// TERMS=3: A fp32 (opt. gather, K=512), 3-term split (fp32-grade).
// TERMS=2: A bf16 (exact),               2-term split.
// Block 128x128, 4 waves (2x2 of 64x64), BK=32, reg-prefetch pipeline.
// W pre-split/transposed: WtH/WtL bf16 [2048 cols][K].
// ============================================================================
template <int TERMS>
__global__ __launch_bounds__(256) void gemm_mfma(
    const void* __restrict__ Av, const unsigned short* __restrict__ WtH,
    const unsigned short* __restrict__ WtL, const float* __restrict__ bias,
    unsigned short* __restrict__ C, int K, const int* __restrict__ gather) {
  // planes: 0=Ah, 1=Al, 2=Wh, 3=Wl ; [128][40] bf16, row stride 80 B
  __shared__ short lds[4][128][40];

  const int tid = threadIdx.x;
  const int bm = blockIdx.x & 255;
  const int bn = blockIdx.x >> 8;
  const int m0 = bm * 128, n0 = bn * 128;
  const int l = tid & 63;
  const int wv = tid >> 6;
  const int wm = wv >> 1, wn = wv & 1;

  // staging role: tid<128 -> A row srow; tid>=128 -> W col srow
  const int srow = tid & 127;
  const bool isA = (tid < 128);

  const float* aSrcF = nullptr;
  const unsigned short* aSrcB = nullptr;
  const unsigned short* wSrcH = nullptr;
  const unsigned short* wSrcL = nullptr;
  if (isA) {
    if (TERMS == 3) {
      const float* A = (const float*)Av;
      size_t r = gather ? (size_t)gather[m0 + srow] : (size_t)(m0 + srow);
      aSrcF = A + r * (size_t)K;
    } else {
      aSrcB = (const unsigned short*)Av + (size_t)(m0 + srow) * K;
    }
  } else {
    wSrcH = WtH + (size_t)(n0 + srow) * K;
    wSrcL = WtL + (size_t)(n0 + srow) * K;
  }

  uint4 rv[8];
  auto LOADS = [&](int k0) {
    if (isA) {
      if (TERMS == 3) {
        const float* s = aSrcF + k0;
#pragma unroll
        for (int i = 0; i < 8; i++) rv[i] = *(const uint4*)(s + i * 4);
      } else {
        const unsigned short* s = aSrcB + k0;
#pragma unroll
        for (int i = 0; i < 4; i++) rv[i] = *(const uint4*)(s + i * 8);
      }
    } else {
#pragma unroll
      for (int i = 0; i < 4; i++) {
        rv[i]     = *(const uint4*)(wSrcH + k0 + i * 8);
        rv[4 + i] = *(const uint4*)(wSrcL + k0 + i * 8);
      }
    }
  };
  auto WRITE = [&]() {
    if (isA) {
      if (TERMS == 3) {
#pragma unroll
        for (int c = 0; c < 4; c++) {
          const float* f = (const float*)&rv[c * 2];
          bf16x8 hh, ll;
#pragma unroll
          for (int e = 0; e < 8; e++) {
            float x = f[e];
            unsigned short h = f2bf(x);
            hh[e] = (short)h;
            ll[e] = (short)f2bf(x - bf2f(h));
          }
          *(bf16x8*)&lds[0][srow][c * 8] = hh;
          *(bf16x8*)&lds[1][srow][c * 8] = ll;
        }
      } else {
#pragma unroll
        for (int c = 0; c < 4; c++)
          *(uint4*)&lds[0][srow][c * 8] = rv[c];
      }
    } else {
#pragma unroll
      for (int c = 0; c < 4; c++) {
        *(uint4*)&lds[2][srow][c * 8] = rv[c];
        *(uint4*)&lds[3][srow][c * 8] = rv[c + 4];
      }
    }
  };

  f32x16 acc[2][2];
#pragma unroll
  for (int rb = 0; rb < 2; rb++)
#pragma unroll
    for (int cb = 0; cb < 2; cb++)
#pragma unroll
      for (int r = 0; r < 16; r++) acc[rb][cb][r] = 0.0f;

  const int arow = wm * 64 + (l & 31);
  const int wcol = wn * 64 + (l & 31);
  const int koffB = (l >> 5) << 3;   // 0 or 8 elems

  LOADS(0);
  for (int k0 = 0; k0 < K; k0 += 32) {
    WRITE();
    __syncthreads();
    if (k0 + 32 < K) LOADS(k0 + 32);
#pragma unroll
    for (int ks = 0; ks < 2; ks++) {
      const int ko = ks * 16 + koffB;
      bf16x8 ah0 = *(const bf16x8*)&lds[0][arow][ko];
      bf16x8 ah1 = *(const bf16x8*)&lds[0][arow + 32][ko];
      bf16x8 wh0 = *(const bf16x8*)&lds[2][wcol][ko];
      bf16x8 wh1 = *(const bf16x8*)&lds[2][wcol + 32][ko];
      bf16x8 wl0 = *(const bf16x8*)&lds[3][wcol][ko];
      bf16x8 wl1 = *(const bf16x8*)&lds[3][wcol + 32][ko];
      acc[0][0] = __builtin_amdgcn_mfma_f32_32x32x16_bf16(ah0, wh0, acc[0][0], 0, 0, 0);
      acc[0][1] = __builtin_amdgcn_mfma_f32_32x32x16_bf16(ah0, wh1, acc[0][1], 0, 0, 0);
      acc[1][0] = __builtin_amdgcn_mfma_f32_32x32x16_bf16(ah1, wh0, acc[1][0], 0, 0, 0);
      acc[1][1] = __builtin_amdgcn_mfma_f32_32x32x16_bf16(ah1, wh1, acc[1][1], 0, 0, 0);
      acc[0][0] = __builtin_amdgcn_mfma_f32_32x32x16_bf16(ah0, wl0, acc[0][0], 0, 0, 0);
      acc[0][1] = __builtin_amdgcn_mfma_f32_32x32x16_bf16(ah0, wl1, acc[0][1], 0, 0, 0);
      acc[1][0] = __builtin_amdgcn_mfma_f32_32x32x16_bf16(ah1, wl0, acc[1][0], 0, 0, 0);
      acc[1][1] = __builtin_amdgcn_mfma_f32_32x32x16_bf16(ah1, wl1, acc[1][1], 0, 0, 0);
      if (TERMS == 3) {
        bf16x8 al0 = *(const bf16x8*)&lds[1][arow][ko];
        bf16x8 al1 = *(const bf16x8*)&lds[1][arow + 32][ko];
        acc[0][0] = __builtin_amdgcn_mfma_f32_32x32x16_bf16(al0, wh0, acc[0][0], 0, 0, 0);
        acc[0][1] = __builtin_amdgcn_mfma_f32_32x32x16_bf16(al0, wh1, acc[0][1], 0, 0, 0);
        acc[1][0] = __builtin_amdgcn_mfma_f32_32x32x16_bf16(al1, wh0, acc[1][0], 0, 0, 0);
        acc[1][1] = __builtin_amdgcn_mfma_f32_32x32x16_bf16(al1, wh1, acc[1][1], 0, 0, 0);
      }
    }
    __syncthreads();
  }

  // epilogue: bias + bf16 store (per r: 32 lanes -> 64B contiguous)
  const float b0 = bias[n0 + wn * 64 + (l & 31)];
  const float b1 = bias[n0 + wn * 64 + 32 + (l & 31)];
#pragma unroll
  for (int rb = 0; rb < 2; rb++) {
    const int rowb = m0 + wm * 64 + rb * 32 + 4 * (l >> 5);
#pragma unroll
    for (int cb = 0; cb < 2; cb++) {
      const int col = n0 + wn * 64 + cb * 32 + (l & 31);
      const float bb = cb ? b1 : b0;
#pragma unroll
      for (int r = 0; r < 16; r++) {
        const int row = rowb + (r & 3) + 8 * (r >> 2);
        C[(size_t)row * 2048 + col] = f2bf(acc[rb][cb][r] + bb);
      }
    }
  }
}

// ============================================================================
// Fused bidirectional recurrence, MFMA edition (round 8, unchanged).
// ============================================================================
__global__ __launch_bounds__(256, 1) void lstm_fused(
    const unsigned short* __restrict__ xzF,
    const unsigned short* __restrict__ xzB,
    const float* __restrict__ UtF,
    const float* __restrict__ UtB,
    float* __restrict__ outF32,
    unsigned short* __restrict__ outB16,
    float* __restrict__ hbuf,
    float* __restrict__ stateh, float* __restrict__ statec,
    unsigned* __restrict__ bar) {
  __shared__ __align__(16) char h_lds[65536];
  __shared__ float p_lds[4][32][36];

  const int tid = threadIdx.x;
  const int bid = blockIdx.x;
  const int dir = bid >> 7;
  const int jg  = (bid & 127) >> 1;
  const int bg  = bid & 1;
  const int grp = dir * 2 + bg;

  const unsigned short* xz = dir ? xzB : xzF;
  const float* Ut = dir ? UtB : UtF;
  char* hbuf_c = (char*)hbuf;

  const int l  = tid & 63;
  const int wv = tid >> 6;

  bf16x8 uh8[8], ul8[8];
  {
    const int c = l & 31;
    const size_t gcol = (size_t)((c >> 3) * 512 + jg * 8 + (c & 7));
#pragma unroll
    for (int ks = 0; ks < 8; ks++) {
      const float* src = Ut + gcol * 512 + (wv * 8 + ks) * 16 + ((l >> 5) << 3);
      bf16x8 hh, ll;
#pragma unroll
      for (int e = 0; e < 8; e++) {
        float f = src[e];
        unsigned short us = f2bf(f);
        hh[e] = (short)us;
        ll[e] = (short)f2bf(f - bf2f(us));
      }
      uh8[ks] = hh;
      ul8[ks] = ll;
    }
  }

  const int ub = tid >> 3;
  const int jl = tid & 7;
  const int b  = bg * 32 + ub;
  const int j  = jg * 8 + jl;

  unsigned* leafArr = bar + grp * 128;
  unsigned* myleaf  = leafArr + (jg & 7) * 16;

  const unsigned short* xzb = xz + (size_t)b * (512 * 2048) + j;

  float creg = 0.0f;
  float zx0, zx1, zx2, zx3;
  {
    const unsigned short* p = xzb + (size_t)(dir ? 511 : 0) * 2048;
    zx0 = bf2f(p[0]); zx1 = bf2f(p[512]);
    zx2 = bf2f(p[1024]); zx3 = bf2f(p[1536]);
  }

  const char* hrow = h_lds + (l & 31) * 1024;
  const int axr = (l & 7) << 4;
  const int koff = (l >> 5) << 4;
  const int hswz_w = (ub & 7) << 4;

  for (int s = 0; s < 512; s++) {
    const int tt = dir ? (511 - s) : s;

    if (s > 0) {
      const char* sb = hbuf_c + (size_t)(grp * 2 + (s & 1)) * 65536;
      float4 hv[16];
#pragma unroll
      for (int i = 0; i < 16; i++) {
        const float* p = (const float*)(sb + (size_t)(i * 256 + tid) * 16);
        asm volatile("global_load_dwordx4 %0, %1, off sc0 sc1"
                     : "=v"(hv[i]) : "v"(p) : "memory");
      }
      asm volatile("s_waitcnt vmcnt(0)" ::: "memory");
      __builtin_amdgcn_sched_barrier(0);
#pragma unroll
      for (int i = 0; i < 16; i++)
        *(float4*)(h_lds + (size_t)(i * 256 + tid) * 16) = hv[i];
    }
    __syncthreads();

    if (s > 0) {
      f32x16 acc;
#pragma unroll
      for (int r = 0; r < 16; r++) acc[r] = 0.0f;
#pragma unroll
      for (int ks = 0; ks < 8; ks++) {
        const int boff = (((wv * 8 + ks) << 5) + koff) ^ axr;
        bf16x8 ahh = *(const bf16x8*)(hrow + boff);
        bf16x8 ahl = *(const bf16x8*)(hrow + 32768 + boff);
        acc = __builtin_amdgcn_mfma_f32_32x32x16_bf16(ahh, uh8[ks], acc, 0, 0, 0);
        acc = __builtin_amdgcn_mfma_f32_32x32x16_bf16(ahl, uh8[ks], acc, 0, 0, 0);
        acc = __builtin_amdgcn_mfma_f32_32x32x16_bf16(ahh, ul8[ks], acc, 0, 0, 0);
      }
#pragma unroll
      for (int r = 0; r < 16; r++) {
        const int row = (r & 3) + 8 * (r >> 2) + 4 * (l >> 5);
        p_lds[wv][row][l & 31] = acc[r];
      }
    }
    __syncthreads();

    float h;
    {
      float z0 = zx0, z1 = zx1, z2 = zx2, z3 = zx3;
      if (s > 0) {
#pragma unroll
        for (int w = 0; w < 4; w++) {
          z0 += p_lds[w][ub][jl];
          z1 += p_lds[w][ub][8 + jl];
          z2 += p_lds[w][ub][16 + jl];
          z3 += p_lds[w][ub][24 + jl];
        }
      }
      float si = fsigmoid(z0);
      float sf = fsigmoid(z1);
      float tg = ftanh(z2);
      float so = fsigmoid(z3);
      creg = fmaf(sf, creg, si * tg);
      h = so * ftanh(creg);
    }

    const int col = dir * 512 + j;
    if (s < 511) {
      unsigned short hhs = f2bf(h);
      unsigned short hls = f2bf(h - bf2f(hhs));
      char* db = hbuf_c + (size_t)(grp * 2 + ((s & 1) ^ 1)) * 65536;
      char* pj = db + ub * 1024 + ((j * 2) ^ hswz_w);
      unsigned vh = hhs, vl = hls;
      asm volatile("global_store_short %0, %1, off sc0 sc1"
                   :: "v"(pj), "v"(vh) : "memory");
      asm volatile("global_store_short %0, %1, off sc0 sc1"
                   :: "v"(pj + 32768), "v"(vl) : "memory");
      asm volatile("s_waitcnt vmcnt(0)" ::: "memory");
      __syncthreads();
      if (tid == 0)
        __hip_atomic_fetch_add(myleaf, 1u, __ATOMIC_RELAXED,
                               __HIP_MEMORY_SCOPE_AGENT);
      if (outB16) outB16[((size_t)b * 512 + tt) * 1024 + col] = f2bf(h);
      else        outF32[((size_t)b * 512 + tt) * 1024 + col] = h;
      {
        const int tn = dir ? (510 - s) : (s + 1);
        const unsigned short* p = xzb + (size_t)tn * 2048;
        zx0 = bf2f(p[0]); zx1 = bf2f(p[512]);
        zx2 = bf2f(p[1024]); zx3 = bf2f(p[1536]);
      }
      if (tid < 8) {
        const unsigned tgt = 8u * (unsigned)(s + 1);
        while (__hip_atomic_load(leafArr + tid * 16, __ATOMIC_RELAXED,
                                 __HIP_MEMORY_SCOPE_AGENT) < tgt)
          __builtin_amdgcn_s_sleep(1);
      }
      __syncthreads();
    } else {
      if (outB16) outB16[((size_t)b * 512 + tt) * 1024 + col] = f2bf(h);
      else        outF32[((size_t)b * 512 + tt) * 1024 + col] = h;
      if (stateh != nullptr) {
        stateh[b * 1024 + col] = h;
        statec[b * 1024 + col] = creg;
      }
    }
  }
}

// ---------------------------------------------------------------------------
extern "C" void kernel_launch(void* const* d_in, const int* in_sizes, int n_in,
                              void* d_out, int out_size, void* d_ws, size_t ws_size,
                              hipStream_t stream) {
  const int*   ids = (const int*)d_in[0];
  const float* emb = (const float*)d_in[1];
  const float* W1f = (const float*)d_in[2];
  const float* U1f = (const float*)d_in[3];
  const float* b1f = (const float*)d_in[4];
  const float* W1b = (const float*)d_in[5];
  const float* U1b = (const float*)d_in[6];
  const float* b1b = (const float*)d_in[7];
  const float* W2f = (const float*)d_in[8];
  const float* U2f = (const float*)d_in[9];
  const float* b2f = (const float*)d_in[10];
  const float* W2b = (const float*)d_in[11];
  const float* U2b = (const float*)d_in[12];
  const float* b2b = (const float*)d_in[13];
  float* out = (float*)d_out;

  char* ws = (char*)d_ws;
  // ws layout (~272.8 MB) — unchanged from round 8:
  unsigned short* xzF = (unsigned short*)(ws + 0ull);
  unsigned short* xzB = (unsigned short*)(ws + 134217728ull);
  float* Ut1f = (float*)(ws + 268435456ull);
  float* Ut1b = Ut1f + 1048576;
  float* Ut2f = Ut1b + 1048576;
  float* Ut2b = Ut2f + 1048576;
  float* hbuf = (float*)(ws + 285212672ull);
  unsigned* bar = (unsigned*)(ws + 285736960ull);

  // d_out stash layout (all dead before the final lstm_fused writes out):
  //   l1d  bf16 [32768][1024]      @ 0          (67,108,864)
  //   Wh1f/Wl1f bf16 [2048][512]   @ 67,108,864 (2 MB each)
  //   Wh1b/Wl1b                    @ 71,303,168
  //   Wh2f/Wl2f bf16 [2048][1024]  @ 75,497,472 (4 MB each)
  //   Wh2b/Wl2b                    @ 83,886,080  (end 92,274,688 < 128.5 MB)
  char* outc = (char*)d_out;
  unsigned short* l1d  = (unsigned short*)outc;
  unsigned short* Wh1f = (unsigned short*)(outc + 67108864ull);
  unsigned short* Wl1f = (unsigned short*)(outc + 69206016ull);
  unsigned short* Wh1b = (unsigned short*)(outc + 71303168ull);
  unsigned short* Wl1b = (unsigned short*)(outc + 73400320ull);
  unsigned short* Wh2f = (unsigned short*)(outc + 75497472ull);
  unsigned short* Wl2f = (unsigned short*)(outc + 79691776ull);
  unsigned short* Wh2b = (unsigned short*)(outc + 83886080ull);
  unsigned short* Wl2b = (unsigned short*)(outc + 88080384ull);

  transpose_u<<<1024, 256, 0, stream>>>(U1f, Ut1f);
  transpose_u<<<1024, 256, 0, stream>>>(U1b, Ut1b);
  transpose_u<<<1024, 256, 0, stream>>>(U2f, Ut2f);
  transpose_u<<<1024, 256, 0, stream>>>(U2b, Ut2b);
  transpose_split<<<1024, 256, 0, stream>>>(W1f, Wh1f, Wl1f, 512);
  transpose_split<<<1024, 256, 0, stream>>>(W1b, Wh1b, Wl1b, 512);
  transpose_split<<<2048, 256, 0, stream>>>(W2f, Wh2f, Wl2f, 1024);
  transpose_split<<<2048, 256, 0, stream>>>(W2b, Wh2b, Wl2b, 1024);

  // layer-1 projections (MFMA, 3-term, emb gather)
  gemm_mfma<3><<<4096, 256, 0, stream>>>(emb, Wh1f, Wl1f, b1f, xzF, 512, ids);
  gemm_mfma<3><<<4096, 256, 0, stream>>>(emb, Wh1b, Wl1b, b1b, xzB, 512, ids);
  hipMemsetAsync(bar, 0, 4096, stream);
  lstm_fused<<<NBLK_LSTM, 256, 0, stream>>>(xzF, xzB, Ut1f, Ut1b,
                                            nullptr, l1d, hbuf,
                                            nullptr, nullptr, bar);
  // layer-2 projections (MFMA, 2-term, A = bf16 l1)
  gemm_mfma<2><<<4096, 256, 0, stream>>>(l1d, Wh2f, Wl2f, b2f, xzF, 1024, nullptr);
  gemm_mfma<2><<<4096, 256, 0, stream>>>(l1d, Wh2b, Wl2b, b2b, xzB, 1024, nullptr);
  hipMemsetAsync(bar, 0, 4096, stream);
  lstm_fused<<<NBLK_LSTM, 256, 0, stream>>>(xzF, xzB, Ut2f, Ut2b,
                                            out, nullptr, hbuf,
                                            out + 33554432, out + 33619968, bar);
}

// Round 10
// 4991.560 us; speedup vs baseline: 28.1791x; 1.5673x over previous
//
#include <hip/hip_runtime.h>
#include <math.h>

// ---------------------------------------------------------------------------
// Encoder: 2-layer bidirectional LSTM, B=64, T=512, E=H=512, fp32 in/out.
// Round 10: GEMMs rebuilt around global_load_lds + pre-swizzled bf16 panels
// ([tile][kt][128][32], granule slot = g ^ (row&3)). All 4 projections are
// C = A_bf16 @ (Wh+Wl) + b with double-buffered LDS, 2-phase pipeline.
// lstm_fused (round-8 MFMA) unchanged except l1 stored in panel layout.
// ---------------------------------------------------------------------------

#define NBLK_LSTM 256

typedef __attribute__((ext_vector_type(8))) short bf16x8;
typedef __attribute__((ext_vector_type(16))) float f32x16;

__device__ __forceinline__ float bf2f(unsigned short u) {
  return __uint_as_float(((unsigned)u) << 16);
}
__device__ __forceinline__ unsigned short f2bf(float f) {
  unsigned u = __float_as_uint(f);
  unsigned r = (u + 0x7FFFu + ((u >> 16) & 1u)) >> 16;
  return (unsigned short)r;
}
__device__ __forceinline__ float fsigmoid(float x) {
  return 1.0f / (1.0f + __expf(-x));
}
__device__ __forceinline__ float ftanh(float x) {
  return 1.0f - 2.0f / (1.0f + __expf(2.0f * x));
}
__device__ __forceinline__ void gload16(const void* g, void* l) {
  __builtin_amdgcn_global_load_lds(
      (const __attribute__((address_space(1))) unsigned int*)g,
      (__attribute__((address_space(3))) unsigned int*)l, 16, 0, 0);
}

// ---------------- U transpose: Ut[col][k] = U[k][col] (fp32) ----------------
__global__ __launch_bounds__(256) void transpose_u(const float* __restrict__ U,
                                                   float* __restrict__ Ut) {
  __shared__ float tile[32][33];
  int kt = blockIdx.x & 15;
  int ct = blockIdx.x >> 4;
  int k0 = kt * 32, c0 = ct * 32;
  int tx = threadIdx.x & 31, ty = threadIdx.x >> 5;
#pragma unroll
  for (int i = 0; i < 32; i += 8)
    tile[ty + i][tx] = U[(size_t)(k0 + ty + i) * 2048 + c0 + tx];
  __syncthreads();
#pragma unroll
  for (int i = 0; i < 32; i += 8)
    Ut[(size_t)(c0 + ty + i) * 512 + k0 + tx] = tile[tx][ty + i];
}

// ---------- W -> split bf16 panels [16 nt][KT][128][32], swizzled ----------
__global__ __launch_bounds__(256) void build_w_panels(
    const float* __restrict__ W, unsigned short* __restrict__ Wh,
    unsigned short* __restrict__ Wl, int KT) {
  __shared__ float tile[32][33];
  const int tid = threadIdx.x;
  int kt = blockIdx.x % KT;
  int ct = blockIdx.x / KT;          // 0..63
  int k0 = kt * 32, c0 = ct * 32;
  int tx = tid & 31, ty = tid >> 5;
#pragma unroll
  for (int i = 0; i < 32; i += 8)
    tile[ty + i][tx] = W[(size_t)(k0 + ty + i) * 2048 + c0 + tx];
  __syncthreads();
  const int t = tid & 127;
  const int cl = t & 31, g = t >> 5;          // col-local, granule 0..3
  const int c = c0 + cl;
  const int rm = c & 127, nt = c >> 7;
  const int slot = g ^ (rm & 3);
  size_t off = (((size_t)(nt * KT + kt) * 128 + rm) << 5) + slot * 8;
  bf16x8 hh, ll;
#pragma unroll
  for (int e = 0; e < 8; e++) {
    float f = tile[g * 8 + e][cl];
    unsigned short h = f2bf(f);
    hh[e] = (short)h;
    ll[e] = (short)f2bf(f - bf2f(h));
  }
  if (tid < 128) *(bf16x8*)(Wh + off) = hh;
  else           *(bf16x8*)(Wl + off) = ll;
}

// ------- A1 panels: bf16(emb[ids[m]]) -> [256 mt][16 kt][128][32] ----------
__global__ __launch_bounds__(256) void build_a1_panels(
    const int* __restrict__ ids, const float* __restrict__ emb,
    unsigned short* __restrict__ Apan) {
  const int tid = threadIdx.x;
  const int l = tid & 63, wv = tid >> 6;
  const int m = blockIdx.x * 4 + wv;
  const float* src = emb + (size_t)ids[m] * 512 + l * 8;
  float4 v0 = *(const float4*)src;
  float4 v1 = *(const float4*)(src + 4);
  float f[8] = {v0.x, v0.y, v0.z, v0.w, v1.x, v1.y, v1.z, v1.w};
  bf16x8 hh;
#pragma unroll
  for (int e = 0; e < 8; e++) hh[e] = (short)f2bf(f[e]);
  const int rm = m & 127, mt = m >> 7;
  const int kt = l >> 2, g = l & 3;
  const int slot = g ^ (rm & 3);
  *(bf16x8*)(Apan + (((size_t)(mt * 16 + kt) * 128 + rm) << 5) + slot * 8) = hh;
}

// ============================================================================
// Panel GEMM: C_bf16[32768][2048] = A @ (Wh + Wl) + bias.
// 128x128 tile, 4 waves (2x2 of 64x64), BK=32, double-buffered LDS,
// global_load_lds staging (6x 16B/lane per tile), 16 MFMA 32x32x16 per tile.
// Panels pre-swizzled (slot = g ^ (row&3)) -> conflict-floor ds_read_b128.
// ============================================================================
template <int KT>
__global__ __launch_bounds__(256) void gemm_panel(
    const unsigned short* __restrict__ Apan,
    const unsigned short* __restrict__ WhP,
    const unsigned short* __restrict__ WlP,
    const float* __restrict__ bias,
    unsigned short* __restrict__ C) {
  __shared__ __align__(16) char lds[2][24576];   // per buf: A 8K | Wh 8K | Wl 8K

  const int tid = threadIdx.x;
  const int mt = blockIdx.x & 255;
  const int nt = blockIdx.x >> 8;
  const int l = tid & 63;
  const int wv = tid >> 6;
  const int wm = wv >> 1, wn = wv & 1;

  const char* aSrc = (const char*)(Apan + (size_t)mt * KT * 4096);
  const char* hSrc = (const char*)(WhP + (size_t)nt * KT * 4096);
  const char* lSrc = (const char*)(WlP + (size_t)nt * KT * 4096);
  const int wvo = wv * 1024;
  const int lo16 = l * 16;

  f32x16 acc[2][2];
#pragma unroll
  for (int rb = 0; rb < 2; rb++)
#pragma unroll
    for (int cb = 0; cb < 2; cb++)
#pragma unroll
      for (int r = 0; r < 16; r++) acc[rb][cb][r] = 0.0f;

  auto STAGE = [&](int buf, int t) {
    const char* ga = aSrc + (size_t)t * 8192 + wvo + lo16;
    const char* gh = hSrc + (size_t)t * 8192 + wvo + lo16;
    const char* gl = lSrc + (size_t)t * 8192 + wvo + lo16;
    char* da = &lds[buf][0] + wvo;
    char* dh = &lds[buf][8192] + wvo;
    char* dl = &lds[buf][16384] + wvo;
    gload16(ga, da);
    gload16(ga + 4096, da + 4096);
    gload16(gh, dh);
    gload16(gh + 4096, dh + 4096);
    gload16(gl, dl);
    gload16(gl + 4096, dl + 4096);
  };

  STAGE(0, 0);
  asm volatile("s_waitcnt vmcnt(0)" ::: "memory");
  __syncthreads();

  const int aoff0 = (wm * 64 + (l & 31)) * 64;
  const int woff0 = 8192 + (wn * 64 + (l & 31)) * 64;
  const int gbase = l >> 5;
  const int gx = l & 3;

  for (int t = 0; t < KT; t++) {
    if (t + 1 < KT) STAGE((t + 1) & 1, t + 1);
    const char* lb = lds[t & 1];
#pragma unroll
    for (int ks = 0; ks < 2; ks++) {
      const int slot = (((ks << 1) + gbase) ^ gx) << 4;
      bf16x8 a0 = *(const bf16x8*)(lb + aoff0 + slot);
      bf16x8 a1 = *(const bf16x8*)(lb + aoff0 + 2048 + slot);
      bf16x8 h0 = *(const bf16x8*)(lb + woff0 + slot);
      bf16x8 h1 = *(const bf16x8*)(lb + woff0 + 2048 + slot);
      bf16x8 w0 = *(const bf16x8*)(lb + woff0 + 8192 + slot);
      bf16x8 w1 = *(const bf16x8*)(lb + woff0 + 8192 + 2048 + slot);
      acc[0][0] = __builtin_amdgcn_mfma_f32_32x32x16_bf16(a0, h0, acc[0][0], 0, 0, 0);
      acc[0][1] = __builtin_amdgcn_mfma_f32_32x32x16_bf16(a0, h1, acc[0][1], 0, 0, 0);
      acc[1][0] = __builtin_amdgcn_mfma_f32_32x32x16_bf16(a1, h0, acc[1][0], 0, 0, 0);
      acc[1][1] = __builtin_amdgcn_mfma_f32_32x32x16_bf16(a1, h1, acc[1][1], 0, 0, 0);
      acc[0][0] = __builtin_amdgcn_mfma_f32_32x32x16_bf16(a0, w0, acc[0][0], 0, 0, 0);
      acc[0][1] = __builtin_amdgcn_mfma_f32_32x32x16_bf16(a0, w1, acc[0][1], 0, 0, 0);
      acc[1][0] = __builtin_amdgcn_mfma_f32_32x32x16_bf16(a1, w0, acc[1][0], 0, 0, 0);
      acc[1][1] = __builtin_amdgcn_mfma_f32_32x32x16_bf16(a1, w1, acc[1][1], 0, 0, 0);
    }
    asm volatile("s_waitcnt vmcnt(0)" ::: "memory");
    __syncthreads();
  }

  const int m0 = mt * 128, n0 = nt * 128;
  const float b0 = bias[n0 + wn * 64 + (l & 31)];
  const float b1 = bias[n0 + wn * 64 + 32 + (l & 31)];
#pragma unroll
  for (int rb = 0; rb < 2; rb++) {
    const int rowb = m0 + wm * 64 + rb * 32 + 4 * (l >> 5);
#pragma unroll
    for (int cb = 0; cb < 2; cb++) {
      const int col = n0 + wn * 64 + cb * 32 + (l & 31);
      const float bb = cb ? b1 : b0;
#pragma unroll
      for (int r = 0; r < 16; r++) {
        const int row = rowb + (r & 3) + 8 * (r >> 2);
        C[(size_t)row * 2048 + col] = f2bf(acc[rb][cb][r] + bb);
      }
    }
  }
}

// ============================================================================
// Fused bidirectional recurrence, MFMA edition (round 8) — unchanged except
// outB16 now writes the layer-2 A-panel layout ([mt][32 kt][128][32], swz).
// ============================================================================
__global__ __launch_bounds__(256, 1) void lstm_fused(
    const unsigned short* __restrict__ xzF,
    const unsigned short* __restrict__ xzB,
    const float* __restrict__ UtF,
    const float* __restrict__ UtB,
    float* __restrict__ outF32,
    unsigned short* __restrict__ outB16,
    float* __restrict__ hbuf,
    float* __restrict__ stateh, float* __restrict__ statec,
    unsigned* __restrict__ bar) {
  __shared__ __align__(16) char h_lds[65536];
  __shared__ float p_lds[4][32][36];

  const int tid = threadIdx.x;
  const int bid = blockIdx.x;
  const int dir = bid >> 7;
  const int jg  = (bid & 127) >> 1;
  const int bg  = bid & 1;
  const int grp = dir * 2 + bg;

  const unsigned short* xz = dir ? xzB : xzF;
  const float* Ut = dir ? UtB : UtF;
  char* hbuf_c = (char*)hbuf;

  const int l  = tid & 63;
  const int wv = tid >> 6;

  bf16x8 uh8[8], ul8[8];
  {
    const int c = l & 31;
    const size_t gcol = (size_t)((c >> 3) * 512 + jg * 8 + (c & 7));
#pragma unroll
    for (int ks = 0; ks < 8; ks++) {
      const float* src = Ut + gcol * 512 + (wv * 8 + ks) * 16 + ((l >> 5) << 3);
      bf16x8 hh, ll;
#pragma unroll
      for (int e = 0; e < 8; e++) {
        float f = src[e];
        unsigned short us = f2bf(f);
        hh[e] = (short)us;
        ll[e] = (short)f2bf(f - bf2f(us));
      }
      uh8[ks] = hh;
      ul8[ks] = ll;
    }
  }

  const int ub = tid >> 3;
  const int jl = tid & 7;
  const int b  = bg * 32 + ub;
  const int j  = jg * 8 + jl;

  unsigned* leafArr = bar + grp * 128;
  unsigned* myleaf  = leafArr + (jg & 7) * 16;

  const unsigned short* xzb = xz + (size_t)b * (512 * 2048) + j;

  float creg = 0.0f;
  float zx0, zx1, zx2, zx3;
  {
    const unsigned short* p = xzb + (size_t)(dir ? 511 : 0) * 2048;
    zx0 = bf2f(p[0]); zx1 = bf2f(p[512]);
    zx2 = bf2f(p[1024]); zx3 = bf2f(p[1536]);
  }

  const char* hrow = h_lds + (l & 31) * 1024;
  const int axr = (l & 7) << 4;
  const int koff = (l >> 5) << 4;
  const int hswz_w = (ub & 7) << 4;

  // l1-panel store constants (col = dir*512 + j)
  const int colp = dir * 512 + j;
  const int p_kt = colp >> 5, p_g = (colp >> 3) & 3, p_e = colp & 7;

  for (int s = 0; s < 512; s++) {
    const int tt = dir ? (511 - s) : s;

    if (s > 0) {
      const char* sb = hbuf_c + (size_t)(grp * 2 + (s & 1)) * 65536;
      float4 hv[16];
#pragma unroll
      for (int i = 0; i < 16; i++) {
        const float* p = (const float*)(sb + (size_t)(i * 256 + tid) * 16);
        asm volatile("global_load_dwordx4 %0, %1, off sc0 sc1"
                     : "=v"(hv[i]) : "v"(p) : "memory");
      }
      asm volatile("s_waitcnt vmcnt(0)" ::: "memory");
      __builtin_amdgcn_sched_barrier(0);
#pragma unroll
      for (int i = 0; i < 16; i++)
        *(float4*)(h_lds + (size_t)(i * 256 + tid) * 16) = hv[i];
    }
    __syncthreads();

    if (s > 0) {
      f32x16 acc;
#pragma unroll
      for (int r = 0; r < 16; r++) acc[r] = 0.0f;
#pragma unroll
      for (int ks = 0; ks < 8; ks++) {
        const int boff = (((wv * 8 + ks) << 5) + koff) ^ axr;
        bf16x8 ahh = *(const bf16x8*)(hrow + boff);
        bf16x8 ahl = *(const bf16x8*)(hrow + 32768 + boff);
        acc = __builtin_amdgcn_mfma_f32_32x32x16_bf16(ahh, uh8[ks], acc, 0, 0, 0);
        acc = __builtin_amdgcn_mfma_f32_32x32x16_bf16(ahl, uh8[ks], acc, 0, 0, 0);
        acc = __builtin_amdgcn_mfma_f32_32x32x16_bf16(ahh, ul8[ks], acc, 0, 0, 0);
      }
#pragma unroll
      for (int r = 0; r < 16; r++) {
        const int row = (r & 3) + 8 * (r >> 2) + 4 * (l >> 5);
        p_lds[wv][row][l & 31] = acc[r];
      }
    }
    __syncthreads();

    float h;
    {
      float z0 = zx0, z1 = zx1, z2 = zx2, z3 = zx3;
      if (s > 0) {
#pragma unroll
        for (int w = 0; w < 4; w++) {
          z0 += p_lds[w][ub][jl];
          z1 += p_lds[w][ub][8 + jl];
          z2 += p_lds[w][ub][16 + jl];
          z3 += p_lds[w][ub][24 + jl];
        }
      }
      float si = fsigmoid(z0);
      float sf = fsigmoid(z1);
      float tg = ftanh(z2);
      float so = fsigmoid(z3);
      creg = fmaf(sf, creg, si * tg);
      h = so * ftanh(creg);
    }

    // output store helper values
    const int m = b * 512 + tt;
    if (s < 511) {
      unsigned short hhs = f2bf(h);
      unsigned short hls = f2bf(h - bf2f(hhs));
      char* db = hbuf_c + (size_t)(grp * 2 + ((s & 1) ^ 1)) * 65536;
      char* pj = db + ub * 1024 + ((j * 2) ^ hswz_w);
      unsigned vh = hhs, vl = hls;
      asm volatile("global_store_short %0, %1, off sc0 sc1"
                   :: "v"(pj), "v"(vh) : "memory");
      asm volatile("global_store_short %0, %1, off sc0 sc1"
                   :: "v"(pj + 32768), "v"(vl) : "memory");
      asm volatile("s_waitcnt vmcnt(0)" ::: "memory");
      __syncthreads();
      if (tid == 0)
        __hip_atomic_fetch_add(myleaf, 1u, __ATOMIC_RELAXED,
                               __HIP_MEMORY_SCOPE_AGENT);
      if (outB16) {
        const int rm = m & 127, mt = m >> 7;
        outB16[(((size_t)(mt * 32 + p_kt) * 128 + rm) << 5) +
               (p_g ^ (rm & 3)) * 8 + p_e] = f2bf(h);
      } else {
        outF32[((size_t)m) * 1024 + colp] = h;
      }
      {
        const int tn = dir ? (510 - s) : (s + 1);
        const unsigned short* p = xzb + (size_t)tn * 2048;
        zx0 = bf2f(p[0]); zx1 = bf2f(p[512]);
        zx2 = bf2f(p[1024]); zx3 = bf2f(p[1536]);
      }
      if (tid < 8) {
        const unsigned tgt = 8u * (unsigned)(s + 1);
        while (__hip_atomic_load(leafArr + tid * 16, __ATOMIC_RELAXED,
                                 __HIP_MEMORY_SCOPE_AGENT) < tgt)
          __builtin_amdgcn_s_sleep(1);
      }
      __syncthreads();
    } else {
      if (outB16) {
        const int rm = m & 127, mt = m >> 7;
        outB16[(((size_t)(mt * 32 + p_kt) * 128 + rm) << 5) +
               (p_g ^ (rm & 3)) * 8 + p_e] = f2bf(h);
      } else {
        outF32[((size_t)m) * 1024 + colp] = h;
      }
      if (stateh != nullptr) {
        stateh[b * 1024 + colp] = h;
        statec[b * 1024 + colp] = creg;
      }
    }
  }
}

// ---------------------------------------------------------------------------
extern "C" void kernel_launch(void* const* d_in, const int* in_sizes, int n_in,
                              void* d_out, int out_size, void* d_ws, size_t ws_size,
                              hipStream_t stream) {
  const int*   ids = (const int*)d_in[0];
  const float* emb = (const float*)d_in[1];
  const float* W1f = (const float*)d_in[2];
  const float* U1f = (const float*)d_in[3];
  const float* b1f = (const float*)d_in[4];
  const float* W1b = (const float*)d_in[5];
  const float* U1b = (const float*)d_in[6];
  const float* b1b = (const float*)d_in[7];
  const float* W2f = (const float*)d_in[8];
  const float* U2f = (const float*)d_in[9];
  const float* b2f = (const float*)d_in[10];
  const float* W2b = (const float*)d_in[11];
  const float* U2b = (const float*)d_in[12];
  const float* b2b = (const float*)d_in[13];
  float* out = (float*)d_out;

  char* ws = (char*)d_ws;
  // ws layout (~272.8 MB) — unchanged:
  unsigned short* xzF = (unsigned short*)(ws + 0ull);
  unsigned short* xzB = (unsigned short*)(ws + 134217728ull);
  float* Ut1f = (float*)(ws + 268435456ull);
  float* Ut1b = Ut1f + 1048576;
  float* Ut2f = Ut1b + 1048576;
  float* Ut2b = Ut2f + 1048576;
  float* hbuf = (float*)(ws + 285212672ull);
  unsigned* bar = (unsigned*)(ws + 285736960ull);

  // d_out stash (all dead before final lstm_fused writes out):
  //   l1pan bf16 panels [256mt][32kt][128][32] @ 0           (67,108,864)
  //   A1pan bf16 panels [256mt][16kt][128][32] @ 67,108,864  (33,554,432)
  //   Wh1f @100,663,296  Wl1f @102,760,448  Wh1b @104,857,600 Wl1b @106,954,752
  //   Wh2f @109,051,904  Wl2f @113,246,208  Wh2b @117,440,512 Wl2b @121,634,816
  //   end 125,829,120 < out bytes 134,742,016
  char* outc = (char*)d_out;
  unsigned short* l1pan = (unsigned short*)outc;
  unsigned short* A1pan = (unsigned short*)(outc + 67108864ull);
  unsigned short* Wh1f = (unsigned short*)(outc + 100663296ull);
  unsigned short* Wl1f = (unsigned short*)(outc + 102760448ull);
  unsigned short* Wh1b = (unsigned short*)(outc + 104857600ull);
  unsigned short* Wl1b = (unsigned short*)(outc + 106954752ull);
  unsigned short* Wh2f = (unsigned short*)(outc + 109051904ull);
  unsigned short* Wl2f = (unsigned short*)(outc + 113246208ull);
  unsigned short* Wh2b = (unsigned short*)(outc + 117440512ull);
  unsigned short* Wl2b = (unsigned short*)(outc + 121634816ull);

  transpose_u<<<1024, 256, 0, stream>>>(U1f, Ut1f);
  transpose_u<<<1024, 256, 0, stream>>>(U1b, Ut1b);
  transpose_u<<<1024, 256, 0, stream>>>(U2f, Ut2f);
  transpose_u<<<1024, 256, 0, stream>>>(U2b, Ut2b);
  build_w_panels<<<1024, 256, 0, stream>>>(W1f, Wh1f, Wl1f, 16);
  build_w_panels<<<1024, 256, 0, stream>>>(W1b, Wh1b, Wl1b, 16);
  build_w_panels<<<2048, 256, 0, stream>>>(W2f, Wh2f, Wl2f, 32);
  build_w_panels<<<2048, 256, 0, stream>>>(W2b, Wh2b, Wl2b, 32);
  build_a1_panels<<<8192, 256, 0, stream>>>(ids, emb, A1pan);

  // layer-1 projections
  gemm_panel<16><<<4096, 256, 0, stream>>>(A1pan, Wh1f, Wl1f, b1f, xzF);
  gemm_panel<16><<<4096, 256, 0, stream>>>(A1pan, Wh1b, Wl1b, b1b, xzB);
  hipMemsetAsync(bar, 0, 4096, stream);
  lstm_fused<<<NBLK_LSTM, 256, 0, stream>>>(xzF, xzB, Ut1f, Ut1b,
                                            nullptr, l1pan, hbuf,
                                            nullptr, nullptr, bar);
  // layer-2 projections
  gemm_panel<32><<<4096, 256, 0, stream>>>(l1pan, Wh2f, Wl2f, b2f, xzF);
  gemm_panel<32><<<4096, 256, 0, stream>>>(l1pan, Wh2b, Wl2b, b2b, xzB);
  hipMemsetAsync(bar, 0, 4096, stream);
  lstm_fused<<<NBLK_LSTM, 256, 0, stream>>>(xzF, xzB, Ut2f, Ut2b,
                                            out, nullptr, hbuf,
                                            out + 33554432, out + 33619968, bar);
}

// Round 11
// 4730.827 us; speedup vs baseline: 29.7322x; 1.0551x over previous
//
#include <hip/hip_runtime.h>
#include <math.h>

// ---------------------------------------------------------------------------
// Encoder: 2-layer bidirectional LSTM, B=64, T=512, E=H=512, fp32 in/out.
// Round 11: recurrence h exchange restructured to granule layout
// [g=j/8][b][8j] so MFMA A-fragments are DIRECT coalesced IF->VGPR loads
// (1KB per instruction). h_lds stage + one syncthreads deleted.
// GEMMs (round-10 panel/global_load_lds) unchanged.
// ---------------------------------------------------------------------------

#define NBLK_LSTM 256

typedef __attribute__((ext_vector_type(8))) short bf16x8;
typedef __attribute__((ext_vector_type(16))) float f32x16;

__device__ __forceinline__ float bf2f(unsigned short u) {
  return __uint_as_float(((unsigned)u) << 16);
}
__device__ __forceinline__ unsigned short f2bf(float f) {
  unsigned u = __float_as_uint(f);
  unsigned r = (u + 0x7FFFu + ((u >> 16) & 1u)) >> 16;
  return (unsigned short)r;
}
__device__ __forceinline__ float fsigmoid(float x) {
  return 1.0f / (1.0f + __expf(-x));
}
__device__ __forceinline__ float ftanh(float x) {
  return 1.0f - 2.0f / (1.0f + __expf(2.0f * x));
}
__device__ __forceinline__ void gload16(const void* g, void* l) {
  __builtin_amdgcn_global_load_lds(
      (const __attribute__((address_space(1))) unsigned int*)g,
      (__attribute__((address_space(3))) unsigned int*)l, 16, 0, 0);
}

// ---------------- U transpose: Ut[col][k] = U[k][col] (fp32) ----------------
__global__ __launch_bounds__(256) void transpose_u(const float* __restrict__ U,
                                                   float* __restrict__ Ut) {
  __shared__ float tile[32][33];
  int kt = blockIdx.x & 15;
  int ct = blockIdx.x >> 4;
  int k0 = kt * 32, c0 = ct * 32;
  int tx = threadIdx.x & 31, ty = threadIdx.x >> 5;
#pragma unroll
  for (int i = 0; i < 32; i += 8)
    tile[ty + i][tx] = U[(size_t)(k0 + ty + i) * 2048 + c0 + tx];
  __syncthreads();
#pragma unroll
  for (int i = 0; i < 32; i += 8)
    Ut[(size_t)(c0 + ty + i) * 512 + k0 + tx] = tile[tx][ty + i];
}

// ---------- W -> split bf16 panels [16 nt][KT][128][32], swizzled ----------
__global__ __launch_bounds__(256) void build_w_panels(
    const float* __restrict__ W, unsigned short* __restrict__ Wh,
    unsigned short* __restrict__ Wl, int KT) {
  __shared__ float tile[32][33];
  const int tid = threadIdx.x;
  int kt = blockIdx.x % KT;
  int ct = blockIdx.x / KT;          // 0..63
  int k0 = kt * 32, c0 = ct * 32;
  int tx = tid & 31, ty = tid >> 5;
#pragma unroll
  for (int i = 0; i < 32; i += 8)
    tile[ty + i][tx] = W[(size_t)(k0 + ty + i) * 2048 + c0 + tx];
  __syncthreads();
  const int t = tid & 127;
  const int cl = t & 31, g = t >> 5;          // col-local, granule 0..3
  const int c = c0 + cl;
  const int rm = c & 127, nt = c >> 7;
  const int slot = g ^ (rm & 3);
  size_t off = (((size_t)(nt * KT + kt) * 128 + rm) << 5) + slot * 8;
  bf16x8 hh, ll;
#pragma unroll
  for (int e = 0; e < 8; e++) {
    float f = tile[g * 8 + e][cl];
    unsigned short h = f2bf(f);
    hh[e] = (short)h;
    ll[e] = (short)f2bf(f - bf2f(h));
  }
  if (tid < 128) *(bf16x8*)(Wh + off) = hh;
  else           *(bf16x8*)(Wl + off) = ll;
}

// ------- A1 panels: bf16(emb[ids[m]]) -> [256 mt][16 kt][128][32] ----------
__global__ __launch_bounds__(256) void build_a1_panels(
    const int* __restrict__ ids, const float* __restrict__ emb,
    unsigned short* __restrict__ Apan) {
  const int tid = threadIdx.x;
  const int l = tid & 63, wv = tid >> 6;
  const int m = blockIdx.x * 4 + wv;
  const float* src = emb + (size_t)ids[m] * 512 + l * 8;
  float4 v0 = *(const float4*)src;
  float4 v1 = *(const float4*)(src + 4);
  float f[8] = {v0.x, v0.y, v0.z, v0.w, v1.x, v1.y, v1.z, v1.w};
  bf16x8 hh;
#pragma unroll
  for (int e = 0; e < 8; e++) hh[e] = (short)f2bf(f[e]);
  const int rm = m & 127, mt = m >> 7;
  const int kt = l >> 2, g = l & 3;
  const int slot = g ^ (rm & 3);
  *(bf16x8*)(Apan + (((size_t)(mt * 16 + kt) * 128 + rm) << 5) + slot * 8) = hh;
}

// ============================================================================
// Panel GEMM (round 10, unchanged): C_bf16 = A @ (Wh + Wl) + bias.
// ============================================================================
template <int KT>
__global__ __launch_bounds__(256) void gemm_panel(
    const unsigned short* __restrict__ Apan,
    const unsigned short* __restrict__ WhP,
    const unsigned short* __restrict__ WlP,
    const float* __restrict__ bias,
    unsigned short* __restrict__ C) {
  __shared__ __align__(16) char lds[2][24576];

  const int tid = threadIdx.x;
  const int mt = blockIdx.x & 255;
  const int nt = blockIdx.x >> 8;
  const int l = tid & 63;
  const int wv = tid >> 6;
  const int wm = wv >> 1, wn = wv & 1;

  const char* aSrc = (const char*)(Apan + (size_t)mt * KT * 4096);
  const char* hSrc = (const char*)(WhP + (size_t)nt * KT * 4096);
  const char* lSrc = (const char*)(WlP + (size_t)nt * KT * 4096);
  const int wvo = wv * 1024;
  const int lo16 = l * 16;

  f32x16 acc[2][2];
#pragma unroll
  for (int rb = 0; rb < 2; rb++)
#pragma unroll
    for (int cb = 0; cb < 2; cb++)
#pragma unroll
      for (int r = 0; r < 16; r++) acc[rb][cb][r] = 0.0f;

  auto STAGE = [&](int buf, int t) {
    const char* ga = aSrc + (size_t)t * 8192 + wvo + lo16;
    const char* gh = hSrc + (size_t)t * 8192 + wvo + lo16;
    const char* gl = lSrc + (size_t)t * 8192 + wvo + lo16;
    char* da = &lds[buf][0] + wvo;
    char* dh = &lds[buf][8192] + wvo;
    char* dl = &lds[buf][16384] + wvo;
    gload16(ga, da);
    gload16(ga + 4096, da + 4096);
    gload16(gh, dh);
    gload16(gh + 4096, dh + 4096);
    gload16(gl, dl);
    gload16(gl + 4096, dl + 4096);
  };

  STAGE(0, 0);
  asm volatile("s_waitcnt vmcnt(0)" ::: "memory");
  __syncthreads();

  const int aoff0 = (wm * 64 + (l & 31)) * 64;
  const int woff0 = 8192 + (wn * 64 + (l & 31)) * 64;
  const int gbase = l >> 5;
  const int gx = l & 3;

  for (int t = 0; t < KT; t++) {
    if (t + 1 < KT) STAGE((t + 1) & 1, t + 1);
    const char* lb = lds[t & 1];
#pragma unroll
    for (int ks = 0; ks < 2; ks++) {
      const int slot = (((ks << 1) + gbase) ^ gx) << 4;
      bf16x8 a0 = *(const bf16x8*)(lb + aoff0 + slot);
      bf16x8 a1 = *(const bf16x8*)(lb + aoff0 + 2048 + slot);
      bf16x8 h0 = *(const bf16x8*)(lb + woff0 + slot);
      bf16x8 h1 = *(const bf16x8*)(lb + woff0 + 2048 + slot);
      bf16x8 w0 = *(const bf16x8*)(lb + woff0 + 8192 + slot);
      bf16x8 w1 = *(const bf16x8*)(lb + woff0 + 8192 + 2048 + slot);
      acc[0][0] = __builtin_amdgcn_mfma_f32_32x32x16_bf16(a0, h0, acc[0][0], 0, 0, 0);
      acc[0][1] = __builtin_amdgcn_mfma_f32_32x32x16_bf16(a0, h1, acc[0][1], 0, 0, 0);
      acc[1][0] = __builtin_amdgcn_mfma_f32_32x32x16_bf16(a1, h0, acc[1][0], 0, 0, 0);
      acc[1][1] = __builtin_amdgcn_mfma_f32_32x32x16_bf16(a1, h1, acc[1][1], 0, 0, 0);
      acc[0][0] = __builtin_amdgcn_mfma_f32_32x32x16_bf16(a0, w0, acc[0][0], 0, 0, 0);
      acc[0][1] = __builtin_amdgcn_mfma_f32_32x32x16_bf16(a0, w1, acc[0][1], 0, 0, 0);
      acc[1][0] = __builtin_amdgcn_mfma_f32_32x32x16_bf16(a1, w0, acc[1][0], 0, 0, 0);
      acc[1][1] = __builtin_amdgcn_mfma_f32_32x32x16_bf16(a1, w1, acc[1][1], 0, 0, 0);
    }
    asm volatile("s_waitcnt vmcnt(0)" ::: "memory");
    __syncthreads();
  }

  const int m0 = mt * 128, n0 = nt * 128;
  const float b0 = bias[n0 + wn * 64 + (l & 31)];
  const float b1 = bias[n0 + wn * 64 + 32 + (l & 31)];
#pragma unroll
  for (int rb = 0; rb < 2; rb++) {
    const int rowb = m0 + wm * 64 + rb * 32 + 4 * (l >> 5);
#pragma unroll
    for (int cb = 0; cb < 2; cb++) {
      const int col = n0 + wn * 64 + cb * 32 + (l & 31);
      const float bb = cb ? b1 : b0;
#pragma unroll
      for (int r = 0; r < 16; r++) {
        const int row = rowb + (r & 3) + 8 * (r >> 2);
        C[(size_t)row * 2048 + col] = f2bf(acc[rb][cb][r] + bb);
      }
    }
  }
}

// ============================================================================
// Fused bidirectional recurrence — direct-to-register A-frag edition.
// 256 blocks: dir = bid>>7, jg = (bid&127)>>1 (8 j-cols), bg = bid&1 (32 b).
// hbuf slice per (grp, parity): plane hh [64 g][32 b][8 j] bf16 (32 KB),
// plane hl at +32 KB. A-frag load: lane l, wave wv, slice ks reads granule
// g = wv*16 + ks*2 + (l>>5), row l&31 -> 1KB coalesced per instruction.
// Producer (ub, jl) writes 2B at jg*512 + ub*16 + jl*2 (block-contiguous).
// ============================================================================
__global__ __launch_bounds__(256, 1) void lstm_fused(
    const unsigned short* __restrict__ xzF,
    const unsigned short* __restrict__ xzB,
    const float* __restrict__ UtF,
    const float* __restrict__ UtB,
    float* __restrict__ outF32,
    unsigned short* __restrict__ outB16,
    float* __restrict__ hbuf,
    float* __restrict__ stateh, float* __restrict__ statec,
    unsigned* __restrict__ bar) {
  __shared__ float p_lds[4][32][36];

  const int tid = threadIdx.x;
  const int bid = blockIdx.x;
  const int dir = bid >> 7;
  const int jg  = (bid & 127) >> 1;
  const int bg  = bid & 1;
  const int grp = dir * 2 + bg;

  const unsigned short* xz = dir ? xzB : xzF;
  const float* Ut = dir ? UtB : UtF;
  char* hbuf_c = (char*)hbuf;

  const int l  = tid & 63;
  const int wv = tid >> 6;

  // ---- U fragments in registers (loop-invariant B operands) ----
  bf16x8 uh8[8], ul8[8];
  {
    const int c = l & 31;
    const size_t gcol = (size_t)((c >> 3) * 512 + jg * 8 + (c & 7));
#pragma unroll
    for (int ks = 0; ks < 8; ks++) {
      const float* src = Ut + gcol * 512 + (wv * 8 + ks) * 16 + ((l >> 5) << 3);
      bf16x8 hh, ll;
#pragma unroll
      for (int e = 0; e < 8; e++) {
        float f = src[e];
        unsigned short us = f2bf(f);
        hh[e] = (short)us;
        ll[e] = (short)f2bf(f - bf2f(us));
      }
      uh8[ks] = hh;
      ul8[ks] = ll;
    }
  }

  const int ub = tid >> 3;
  const int jl = tid & 7;
  const int b  = bg * 32 + ub;
  const int j  = jg * 8 + jl;

  unsigned* leafArr = bar + grp * 128;
  unsigned* myleaf  = leafArr + (jg & 7) * 16;

  const unsigned short* xzb = xz + (size_t)b * (512 * 2048) + j;

  float creg = 0.0f;
  float zx0, zx1, zx2, zx3;
  {
    const unsigned short* p = xzb + (size_t)(dir ? 511 : 0) * 2048;
    zx0 = bf2f(p[0]); zx1 = bf2f(p[512]);
    zx2 = bf2f(p[1024]); zx3 = bf2f(p[1536]);
  }

  // A-frag load offset: granule (wv*16 + ks*2 + (l>>5)), row (l&31)
  const int aoff = ((wv * 16 + (l >> 5)) * 32 + (l & 31)) * 16;
  // producer store offset (within plane)
  const int poff = jg * 512 + ub * 16 + jl * 2;

  // l1-panel store constants (col = dir*512 + j)
  const int colp = dir * 512 + j;
  const int p_kt = colp >> 5, p_g = (colp >> 3) & 3, p_e = colp & 7;

  for (int s = 0; s < 512; s++) {
    const int tt = dir ? (511 - s) : s;

    if (s > 0) {
      // ---- direct IF->VGPR A-frag loads (coalesced granules) ----
      const char* sb = hbuf_c + (size_t)(grp * 2 + (s & 1)) * 65536;
      bf16x8 ahh[8], ahl[8];
#pragma unroll
      for (int ks = 0; ks < 8; ks++) {
        const char* p = sb + aoff + ks * 1024;
        asm volatile("global_load_dwordx4 %0, %1, off sc0 sc1"
                     : "=v"(ahh[ks]) : "v"(p) : "memory");
        asm volatile("global_load_dwordx4 %0, %1, off sc0 sc1"
                     : "=v"(ahl[ks]) : "v"(p + 32768) : "memory");
      }
      asm volatile("s_waitcnt vmcnt(0)" ::: "memory");
      __builtin_amdgcn_sched_barrier(0);

      f32x16 acc;
#pragma unroll
      for (int r = 0; r < 16; r++) acc[r] = 0.0f;
#pragma unroll
      for (int ks = 0; ks < 8; ks++) {
        acc = __builtin_amdgcn_mfma_f32_32x32x16_bf16(ahh[ks], uh8[ks], acc, 0, 0, 0);
        acc = __builtin_amdgcn_mfma_f32_32x32x16_bf16(ahl[ks], uh8[ks], acc, 0, 0, 0);
        acc = __builtin_amdgcn_mfma_f32_32x32x16_bf16(ahh[ks], ul8[ks], acc, 0, 0, 0);
      }
      // C layout: col = l&31, row = (r&3) + 8*(r>>2) + 4*(l>>5)
#pragma unroll
      for (int r = 0; r < 16; r++) {
        const int row = (r & 3) + 8 * (r >> 2) + 4 * (l >> 5);
        p_lds[wv][row][l & 31] = acc[r];
      }
    }
    __syncthreads();

    // ---- update: thread owns (b, j); 4-way K-reduce folded in ----
    float h;
    {
      float z0 = zx0, z1 = zx1, z2 = zx2, z3 = zx3;
      if (s > 0) {
#pragma unroll
        for (int w = 0; w < 4; w++) {
          z0 += p_lds[w][ub][jl];
          z1 += p_lds[w][ub][8 + jl];
          z2 += p_lds[w][ub][16 + jl];
          z3 += p_lds[w][ub][24 + jl];
        }
      }
      float si = fsigmoid(z0);
      float sf = fsigmoid(z1);
      float tg = ftanh(z2);
      float so = fsigmoid(z3);
      creg = fmaf(sf, creg, si * tg);
      h = so * ftanh(creg);
    }

    const int m = b * 512 + tt;
    if (s < 511) {
      // ---- h store: granule layout, split bf16 pair, IF-coherent ----
      unsigned short hhs = f2bf(h);
      unsigned short hls = f2bf(h - bf2f(hhs));
      char* db = hbuf_c + (size_t)(grp * 2 + ((s & 1) ^ 1)) * 65536;
      char* pj = db + poff;
      unsigned vh = hhs, vl = hls;
      asm volatile("global_store_short %0, %1, off sc0 sc1"
                   :: "v"(pj), "v"(vh) : "memory");
      asm volatile("global_store_short %0, %1, off sc0 sc1"
                   :: "v"(pj + 32768), "v"(vl) : "memory");
      asm volatile("s_waitcnt vmcnt(0)" ::: "memory");
      __syncthreads();
      if (tid == 0)
        __hip_atomic_fetch_add(myleaf, 1u, __ATOMIC_RELAXED,
                               __HIP_MEMORY_SCOPE_AGENT);
      // ---- barrier shadow: output store + next-xz prefetch ----
      if (outB16) {
        const int rm = m & 127, mt = m >> 7;
        outB16[(((size_t)(mt * 32 + p_kt) * 128 + rm) << 5) +
               (p_g ^ (rm & 3)) * 8 + p_e] = f2bf(h);
      } else {
        outF32[((size_t)m) * 1024 + colp] = h;
      }
      {
        const int tn = dir ? (510 - s) : (s + 1);
        const unsigned short* p = xzb + (size_t)tn * 2048;
        zx0 = bf2f(p[0]); zx1 = bf2f(p[512]);
        zx2 = bf2f(p[1024]); zx3 = bf2f(p[1536]);
      }
      if (tid < 8) {
        const unsigned tgt = 8u * (unsigned)(s + 1);
        while (__hip_atomic_load(leafArr + tid * 16, __ATOMIC_RELAXED,
                                 __HIP_MEMORY_SCOPE_AGENT) < tgt)
          __builtin_amdgcn_s_sleep(1);
      }
      __syncthreads();
    } else {
      if (outB16) {
        const int rm = m & 127, mt = m >> 7;
        outB16[(((size_t)(mt * 32 + p_kt) * 128 + rm) << 5) +
               (p_g ^ (rm & 3)) * 8 + p_e] = f2bf(h);
      } else {
        outF32[((size_t)m) * 1024 + colp] = h;
      }
      if (stateh != nullptr) {
        stateh[b * 1024 + colp] = h;
        statec[b * 1024 + colp] = creg;
      }
    }
  }
}

// ---------------------------------------------------------------------------
extern "C" void kernel_launch(void* const* d_in, const int* in_sizes, int n_in,
                              void* d_out, int out_size, void* d_ws, size_t ws_size,
                              hipStream_t stream) {
  const int*   ids = (const int*)d_in[0];
  const float* emb = (const float*)d_in[1];
  const float* W1f = (const float*)d_in[2];
  const float* U1f = (const float*)d_in[3];
  const float* b1f = (const float*)d_in[4];
  const float* W1b = (const float*)d_in[5];
  const float* U1b = (const float*)d_in[6];
  const float* b1b = (const float*)d_in[7];
  const float* W2f = (const float*)d_in[8];
  const float* U2f = (const float*)d_in[9];
  const float* b2f = (const float*)d_in[10];
  const float* W2b = (const float*)d_in[11];
  const float* U2b = (const float*)d_in[12];
  const float* b2b = (const float*)d_in[13];
  float* out = (float*)d_out;

  char* ws = (char*)d_ws;
  unsigned short* xzF = (unsigned short*)(ws + 0ull);
  unsigned short* xzB = (unsigned short*)(ws + 134217728ull);
  float* Ut1f = (float*)(ws + 268435456ull);
  float* Ut1b = Ut1f + 1048576;
  float* Ut2f = Ut1b + 1048576;
  float* Ut2b = Ut2f + 1048576;
  float* hbuf = (float*)(ws + 285212672ull);
  unsigned* bar = (unsigned*)(ws + 285736960ull);

  char* outc = (char*)d_out;
  unsigned short* l1pan = (unsigned short*)outc;
  unsigned short* A1pan = (unsigned short*)(outc + 67108864ull);
  unsigned short* Wh1f = (unsigned short*)(outc + 100663296ull);
  unsigned short* Wl1f = (unsigned short*)(outc + 102760448ull);
  unsigned short* Wh1b = (unsigned short*)(outc + 104857600ull);
  unsigned short* Wl1b = (unsigned short*)(outc + 106954752ull);
  unsigned short* Wh2f = (unsigned short*)(outc + 109051904ull);
  unsigned short* Wl2f = (unsigned short*)(outc + 113246208ull);
  unsigned short* Wh2b = (unsigned short*)(outc + 117440512ull);
  unsigned short* Wl2b = (unsigned short*)(outc + 121634816ull);

  transpose_u<<<1024, 256, 0, stream>>>(U1f, Ut1f);
  transpose_u<<<1024, 256, 0, stream>>>(U1b, Ut1b);
  transpose_u<<<1024, 256, 0, stream>>>(U2f, Ut2f);
  transpose_u<<<1024, 256, 0, stream>>>(U2b, Ut2b);
  build_w_panels<<<1024, 256, 0, stream>>>(W1f, Wh1f, Wl1f, 16);
  build_w_panels<<<1024, 256, 0, stream>>>(W1b, Wh1b, Wl1b, 16);
  build_w_panels<<<2048, 256, 0, stream>>>(W2f, Wh2f, Wl2f, 32);
  build_w_panels<<<2048, 256, 0, stream>>>(W2b, Wh2b, Wl2b, 32);
  build_a1_panels<<<8192, 256, 0, stream>>>(ids, emb, A1pan);

  // layer-1 projections
  gemm_panel<16><<<4096, 256, 0, stream>>>(A1pan, Wh1f, Wl1f, b1f, xzF);
  gemm_panel<16><<<4096, 256, 0, stream>>>(A1pan, Wh1b, Wl1b, b1b, xzB);
  hipMemsetAsync(bar, 0, 4096, stream);
  lstm_fused<<<NBLK_LSTM, 256, 0, stream>>>(xzF, xzB, Ut1f, Ut1b,
                                            nullptr, l1pan, hbuf,
                                            nullptr, nullptr, bar);
  // layer-2 projections
  gemm_panel<32><<<4096, 256, 0, stream>>>(l1pan, Wh2f, Wl2f, b2f, xzF);
  gemm_panel<32><<<4096, 256, 0, stream>>>(l1pan, Wh2b, Wl2b, b2b, xzB);
  hipMemsetAsync(bar, 0, 4096, stream);
  lstm_fused<<<NBLK_LSTM, 256, 0, stream>>>(xzF, xzB, Ut2f, Ut2b,
                                            out, nullptr, hbuf,
                                            out + 33554432, out + 33619968, bar);
}